// Round 10
// baseline (207.422 us; speedup 1.0000x reference)
//
#include <hip/hip_runtime.h>
#include <hip/hip_bf16.h>

// Problem constants
#define B_  512
#define H_  256
#define TK_ 512
#define V_  50000
#define NOOV_ 64
#define VE_ (V_ + NOOV_)   // 50064
#define NCB_ 391           // ceil(50000/128)
#define VPAD_ 50176        // 392*128, padded Wo2_bf rows
#define ELOFF 25032        // float offset of bf16 exp-stash inside each out row

typedef __bf16 bf16_t;
typedef __bf16 bf16x8 __attribute__((ext_vector_type(8)));
typedef float  f32x4  __attribute__((ext_vector_type(4)));

#define DEVI __device__ __forceinline__

DEVI float fast_rcp(float x) { return __builtin_amdgcn_rcpf(x); }
DEVI float fast_tanh(float x) {
    float e = __expf(2.f * x);
    return 1.f - 2.f * fast_rcp(e + 1.f);
}
DEVI float fast_sig(float x) { return fast_rcp(1.f + __expf(-x)); }

DEVI unsigned f2bf1(float f) {
    unsigned u = __float_as_uint(f);
    return (u + 0x7fffu + ((u >> 16) & 1u)) >> 16;   // RNE
}

DEVI uint4 cvt8(const float* p) {
    float4 a = *reinterpret_cast<const float4*>(p);
    float4 b = *reinterpret_cast<const float4*>(p + 4);
    bf16x8 v;
    v[0] = (__bf16)a.x; v[1] = (__bf16)a.y; v[2] = (__bf16)a.z; v[3] = (__bf16)a.w;
    v[4] = (__bf16)b.x; v[5] = (__bf16)b.y; v[6] = (__bf16)b.z; v[7] = (__bf16)b.w;
    return *reinterpret_cast<uint4*>(&v);
}

DEVI void gload_lds16(const void* g, void* l) {
    __builtin_amdgcn_global_load_lds(
        (const __attribute__((address_space(1))) void*)g,
        (__attribute__((address_space(3))) void*)l, 16, 0, 0);
}

// ---------------------------------------------------------------------------
// All small conversions / gathers in one kernel (uint4-granular items)
// Wcat gate-interleaved; also precomputes Em = exp(2*mem) for attn.
// ---------------------------------------------------------------------------
#define PR_O1 24576    // Wx end
#define PR_O2 57344    // Wdp end
#define PR_O3 81920    // Wo1 end
#define PR_O4 147456   // Wcat end
#define PR_O5 196608   // xcat end
#define PR_O6 212992   // xh-h0 end
#define PR_EM 245760   // Em end (32768 items of 8 floats)
#define PR_END 245888  // bsum end

__global__ __launch_bounds__(256) void prep_small(
        const float* __restrict__ Wx, const float* __restrict__ Wdp,
        const float* __restrict__ Wo1,
        const float* __restrict__ Wih, const float* __restrict__ Whh,
        const float* __restrict__ bih, const float* __restrict__ bhh,
        const int* __restrict__ y, const float* __restrict__ ct1,
        const float* __restrict__ emb, const float* __restrict__ h0,
        const float* __restrict__ mem,
        unsigned short* __restrict__ Wx_bf, unsigned short* __restrict__ Wdp_bf,
        unsigned short* __restrict__ Wo1_bf, unsigned short* __restrict__ Wcat_bf,
        unsigned short* __restrict__ xcat_bf, unsigned short* __restrict__ xh_bf,
        float* __restrict__ Em, float* __restrict__ bsum) {
    int idx = blockIdx.x * 256 + threadIdx.x;
    if (idx >= PR_END) return;
    if (idx < PR_O1) {
        reinterpret_cast<uint4*>(Wx_bf)[idx] = cvt8(Wx + (size_t)idx * 8);
    } else if (idx < PR_O2) {
        int i = idx - PR_O1;
        reinterpret_cast<uint4*>(Wdp_bf)[i] = cvt8(Wdp + (size_t)i * 8);
    } else if (idx < PR_O3) {
        int i = idx - PR_O2;
        reinterpret_cast<uint4*>(Wo1_bf)[i] = cvt8(Wo1 + (size_t)i * 8);
    } else if (idx < PR_O4) {
        int i = idx - PR_O3;
        int rp = i >> 6, c = (i & 63) * 8;
        int g = rp & 3, j = rp >> 2;
        const float* src = (c < 256) ? &Wih[(size_t)(g * 256 + j) * 256 + c]
                                     : &Whh[(size_t)(g * 256 + j) * 256 + (c - 256)];
        *reinterpret_cast<uint4*>(&Wcat_bf[(size_t)rp * 512 + c]) = cvt8(src);
    } else if (idx < PR_O5) {
        int i = idx - PR_O4;
        int b = i / 96, j = (i - b * 96) * 8;
        const float* src = (j < 512) ? &ct1[(size_t)b * 512 + j]
                                     : &emb[(size_t)y[b] * 256 + (j - 512)];
        *reinterpret_cast<uint4*>(&xcat_bf[(size_t)b * 768 + j]) = cvt8(src);
    } else if (idx < PR_O6) {
        int i = idx - PR_O5;
        int b = i >> 5, c = (i & 31) * 8;
        *reinterpret_cast<uint4*>(&xh_bf[(size_t)b * 512 + 256 + c]) =
            cvt8(&h0[(size_t)b * 256 + c]);
    } else if (idx < PR_EM) {
        int i = idx - PR_O6;
        const float* src = mem + (size_t)i * 8;
        float4 a = *reinterpret_cast<const float4*>(src);
        float4 b = *reinterpret_cast<const float4*>(src + 4);
        float4 ea, eb;
        ea.x = __expf(2.f * a.x); ea.y = __expf(2.f * a.y);
        ea.z = __expf(2.f * a.z); ea.w = __expf(2.f * a.w);
        eb.x = __expf(2.f * b.x); eb.y = __expf(2.f * b.y);
        eb.z = __expf(2.f * b.z); eb.w = __expf(2.f * b.w);
        *reinterpret_cast<float4*>(Em + (size_t)i * 8) = ea;
        *reinterpret_cast<float4*>(Em + (size_t)i * 8 + 4) = eb;
    } else {
        int g0 = (idx - PR_EM) * 8;
#pragma unroll
        for (int k = 0; k < 8; ++k) {
            int rp = g0 + k;
            int g = rp & 3, j = rp >> 2;
            bsum[rp] = bih[g * 256 + j] + bhh[g * 256 + j];
        }
    }
}

// ---------------------------------------------------------------------------
// Small GEMM: C[M,N] = A[M,K](bf16) * B[N,K]^T(bf16) + bias
// BM=BN=64, BK=64, 256 threads. mode: 0 none, 1 relu, 2 exp(2x) (Cf only).
// ---------------------------------------------------------------------------
__global__ __launch_bounds__(256) void gemm64(const unsigned short* __restrict__ Abf,
                                              const unsigned short* __restrict__ Bbf,
                                              const float* __restrict__ bias,
                                              float* __restrict__ Cf,
                                              unsigned short* __restrict__ Cb,
                                              int N, int K, int ldcb, int ocb,
                                              int mode) {
    __shared__ unsigned short As[2][4096];
    __shared__ unsigned short Bs[2][4096];
    const int tid = threadIdx.x;
    const int m0 = blockIdx.y * 64;
    const int n0 = blockIdx.x * 64;
    const int lane = tid & 63;
    const int wid = tid >> 6;
    const int wm = wid >> 1, wn = wid & 1;
    const int r16 = lane & 15, kq = lane >> 4;
    const int lrow = lane >> 3;               // 0..7
    const int lcol = (lane & 7) ^ lrow;       // swizzled source 16B-chunk
    const int ch0 = wid * 2;                  // 2 chunks/wave/matrix (8 total)

    f32x4 acc[2][2] = {};
    const int nt = K >> 6;

#define G64_STAGE(p, k0)                                                       \
    {                                                                          \
        _Pragma("unroll")                                                      \
        for (int i = 0; i < 2; ++i) {                                          \
            int ch = ch0 + i;                                                  \
            int row = ch * 8 + lrow;                                           \
            gload_lds16(&Abf[(size_t)(m0 + row) * K + (k0) + lcol * 8],        \
                        &As[p][ch * 512]);                                     \
            gload_lds16(&Bbf[(size_t)(n0 + row) * K + (k0) + lcol * 8],        \
                        &Bs[p][ch * 512]);                                     \
        }                                                                      \
    }

    G64_STAGE(0, 0);
    __syncthreads();
    int cur = 0;
    for (int t = 0; t < nt; ++t) {
        if (t + 1 < nt) G64_STAGE(cur ^ 1, (t + 1) << 6);
#pragma unroll
        for (int ks = 0; ks < 64; ks += 32) {
            int cbase = (ks >> 3) + kq;
            bf16x8 af[2], bfv[2];
#pragma unroll
            for (int mi = 0; mi < 2; ++mi) {
                int row = wm * 32 + mi * 16 + r16;
                af[mi] = *reinterpret_cast<const bf16x8*>(
                    &As[cur][row * 64 + (cbase ^ (row & 7)) * 8]);
            }
#pragma unroll
            for (int ni = 0; ni < 2; ++ni) {
                int row = wn * 32 + ni * 16 + r16;
                bfv[ni] = *reinterpret_cast<const bf16x8*>(
                    &Bs[cur][row * 64 + (cbase ^ (row & 7)) * 8]);
            }
#pragma unroll
            for (int mi = 0; mi < 2; ++mi)
#pragma unroll
                for (int ni = 0; ni < 2; ++ni)
                    acc[mi][ni] = __builtin_amdgcn_mfma_f32_16x16x32_bf16(af[mi], bfv[ni], acc[mi][ni], 0, 0, 0);
        }
        __syncthreads();
        cur ^= 1;
    }

#pragma unroll
    for (int mi = 0; mi < 2; ++mi)
#pragma unroll
        for (int ni = 0; ni < 2; ++ni) {
            int c = n0 + wn * 32 + ni * 16 + r16;
            float bv = bias[c];
#pragma unroll
            for (int r = 0; r < 4; ++r) {
                int rr = m0 + wm * 32 + mi * 16 + kq * 4 + r;
                float v = acc[mi][ni][r] + bv;
                if (mode == 1) v = fmaxf(v, 0.f);
                if (mode == 2) v = __expf(2.f * v);
                if (Cf) Cf[(size_t)rr * N + c] = v;
                if (Cb) Cb[(size_t)rr * ldcb + ocb + c] = (unsigned short)f2bf1(v);
            }
        }
}

// ---------------------------------------------------------------------------
// Gates GEMM + fused LSTM pointwise. (round-8 proven structure)
// ---------------------------------------------------------------------------
__global__ __launch_bounds__(256) void gemm_lstm(const unsigned short* __restrict__ Abf,
                                                 const unsigned short* __restrict__ Bbf,
                                                 const float* __restrict__ bsum,
                                                 const float* __restrict__ c0,
                                                 float* __restrict__ outH,
                                                 float* __restrict__ outC,
                                                 float* __restrict__ scat,
                                                 unsigned short* __restrict__ scat_bf,
                                                 unsigned short* __restrict__ hc_bf) {
    __shared__ unsigned short As[2][4096];
    __shared__ unsigned short Bs[2][4096];
    __shared__ float gsh[64][68];
    const int tid = threadIdx.x;
    const int m0 = blockIdx.y * 64;
    const int n0 = blockIdx.x * 64;
    const int lane = tid & 63;
    const int wid = tid >> 6;
    const int wm = wid >> 1, wn = wid & 1;
    const int r16 = lane & 15, kq = lane >> 4;
    const int lrow = lane >> 3;
    const int lcol = (lane & 7) ^ lrow;
    const int ch0 = wid * 2;

    f32x4 acc[2][2] = {};

#define GL_STAGE(p, k0)                                                        \
    {                                                                          \
        _Pragma("unroll")                                                      \
        for (int i = 0; i < 2; ++i) {                                          \
            int ch = ch0 + i;                                                  \
            int row = ch * 8 + lrow;                                           \
            gload_lds16(&Abf[(size_t)(m0 + row) * 512 + (k0) + lcol * 8],      \
                        &As[p][ch * 512]);                                     \
            gload_lds16(&Bbf[(size_t)(n0 + row) * 512 + (k0) + lcol * 8],      \
                        &Bs[p][ch * 512]);                                     \
        }                                                                      \
    }

    GL_STAGE(0, 0);
    __syncthreads();
    int cur = 0;
#pragma unroll
    for (int t = 0; t < 8; ++t) {
        if (t < 7) GL_STAGE(cur ^ 1, (t + 1) << 6);
#pragma unroll
        for (int ks = 0; ks < 64; ks += 32) {
            int cbase = (ks >> 3) + kq;
            bf16x8 af[2], bfv[2];
#pragma unroll
            for (int mi = 0; mi < 2; ++mi) {
                int row = wm * 32 + mi * 16 + r16;
                af[mi] = *reinterpret_cast<const bf16x8*>(
                    &As[cur][row * 64 + (cbase ^ (row & 7)) * 8]);
            }
#pragma unroll
            for (int ni = 0; ni < 2; ++ni) {
                int row = wn * 32 + ni * 16 + r16;
                bfv[ni] = *reinterpret_cast<const bf16x8*>(
                    &Bs[cur][row * 64 + (cbase ^ (row & 7)) * 8]);
            }
#pragma unroll
            for (int mi = 0; mi < 2; ++mi)
#pragma unroll
                for (int ni = 0; ni < 2; ++ni)
                    acc[mi][ni] = __builtin_amdgcn_mfma_f32_16x16x32_bf16(af[mi], bfv[ni], acc[mi][ni], 0, 0, 0);
        }
        __syncthreads();
        cur ^= 1;
    }

#pragma unroll
    for (int mi = 0; mi < 2; ++mi)
#pragma unroll
        for (int ni = 0; ni < 2; ++ni) {
            int cl = wn * 32 + ni * 16 + r16;
            float bv = bsum[n0 + cl];
#pragma unroll
            for (int r = 0; r < 4; ++r) {
                int rl = wm * 32 + mi * 16 + kq * 4 + r;
                gsh[rl][cl] = acc[mi][ni][r] + bv;
            }
        }
    __syncthreads();
    const int j0 = n0 >> 2;
#pragma unroll
    for (int u = tid; u < 1024; u += 256) {
        int bl = u >> 4, jl = u & 15;
        float4 g4 = *reinterpret_cast<const float4*>(&gsh[bl][jl * 4]);
        int b = m0 + bl, j = j0 + jl;
        float ig = fast_sig(g4.x);
        float fg = fast_sig(g4.y);
        float gg = fast_tanh(g4.z);
        float og = fast_sig(g4.w);
        float c = fg * c0[(size_t)b * 256 + j] + ig * gg;
        float h = og * fast_tanh(c);
        outH[(size_t)b * 256 + j] = h;
        outC[(size_t)b * 256 + j] = c;
        scat[(size_t)b * 512 + j] = h;
        scat[(size_t)b * 512 + 256 + j] = c;
        unsigned short hb = (unsigned short)f2bf1(h);
        unsigned short cbf = (unsigned short)f2bf1(c);
        scat_bf[(size_t)b * 512 + j] = hb;
        scat_bf[(size_t)b * 512 + 256 + j] = cbf;
        hc_bf[(size_t)b * 768 + j] = hb;
    }
}

// ---------------------------------------------------------------------------
// Vocab GEMM, full-K in LDS: A[128,256] (64KB) + B[128,256] (64KB) staged in
// ONE shot (8 gload_lds/lane) -> single vmcnt drain + single barrier -> 8
// pure-LDS K-steps, zero further sync. 1024 thr = 16 waves (8 wm x 2 wn),
// 1 block/CU. Chunk swizzle: 1KB chunk = 2 rows x 512B; low-3 bits of the
// 16B-chunk index XORed with row&7 on BOTH source and read.
// 1D grid 1564, XCD-swizzled so the 4 m-blocks of a cb share an XCD L2.
// ---------------------------------------------------------------------------
__global__ __launch_bounds__(1024, 4) void gemm_sum(const unsigned short* __restrict__ Abf,
                                                    const unsigned short* __restrict__ Bbf,
                                                    const float* __restrict__ bo2,
                                                    float* __restrict__ outF,
                                                    float* __restrict__ ps) {
    __shared__ unsigned short As[32768];
    __shared__ unsigned short Bs[32768];
    const int f = blockIdx.x;
    int cb, mB;
    if (f < 1536) { cb = (f >> 5) * 8 + (f & 7); mB = (f >> 3) & 3; }
    else { int t = f - 1536; cb = 384 + t % 7; mB = t / 7; }
    const int tid = threadIdx.x;
    const int m0 = mB * 128;
    const int n0 = cb * 128;
    const int lane = tid & 63;
    const int wid = tid >> 6;                 // 0..15
    const int wm = wid >> 1, wn = wid & 1;    // 8 x 2
    const int r16 = lane & 15, kq = lane >> 4;

    // one-shot staging: 64 chunks (1KB = 2 rows x 512B) per matrix, 4/wave
    {
        const int crow = lane >> 5;           // row within chunk (0/1)
        const int ccol = lane & 31;           // 16B-chunk within row
#pragma unroll
        for (int i = 0; i < 4; ++i) {
            int ch = wid * 4 + i;             // 0..63
            int row = ch * 2 + crow;          // 0..127
            int sc = (ccol & 24) | ((ccol ^ row) & 7);
            gload_lds16(&Abf[(size_t)(m0 + row) * 256 + sc * 8], &As[ch * 512]);
            gload_lds16(&Bbf[(size_t)(n0 + row) * 256 + sc * 8], &Bs[ch * 512]);
        }
    }
    __syncthreads();

    f32x4 acc[4] = {};
    const int arow = wm * 16 + r16;
    const unsigned short* aBase = &As[arow * 256];
#pragma unroll
    for (int t = 0; t < 8; ++t) {
        const int cbase = t * 4 + kq;         // 0..31
        const int cA = (cbase & 24) | ((cbase ^ arow) & 7);
        bf16x8 af = *reinterpret_cast<const bf16x8*>(&aBase[cA * 8]);
#pragma unroll
        for (int ni = 0; ni < 4; ++ni) {
            int brow = wn * 64 + ni * 16 + r16;
            int cB = (cbase & 24) | ((cbase ^ brow) & 7);
            bf16x8 bv = *reinterpret_cast<const bf16x8*>(&Bs[brow * 256 + cB * 8]);
            acc[ni] = __builtin_amdgcn_mfma_f32_16x16x32_bf16(af, bv, acc[ni], 0, 0, 0);
        }
    }

    float psum[4] = {0.f, 0.f, 0.f, 0.f};
#pragma unroll
    for (int ni = 0; ni < 4; ++ni) {
        int c = n0 + wn * 64 + ni * 16 + r16;
        bool ok = (c < V_);
        float bv = ok ? bo2[c] : 0.f;
#pragma unroll
        for (int r = 0; r < 4; ++r) {
            int rr = m0 + wm * 16 + kq * 4 + r;
            float p = __expf(acc[ni][r] + bv);
            unsigned eb = f2bf1(p);
            if (ok) {
                unsigned short* el =
                    (unsigned short*)(outF + (size_t)rr * VE_ + ELOFF);
                el[c] = (unsigned short)eb;
                psum[r] += __uint_as_float(eb << 16);
            }
        }
    }

#pragma unroll
    for (int r = 0; r < 4; ++r) {
        float v = psum[r];
        v += __shfl_xor(v, 1);
        v += __shfl_xor(v, 2);
        v += __shfl_xor(v, 4);
        v += __shfl_xor(v, 8);
        if (r16 == 0) {
            int rr = m0 + wm * 16 + kq * 4 + r;
            ps[((size_t)cb * 512 + rr) * 2 + wn] = v;
        }
    }
}

// ---------------------------------------------------------------------------
// Fused: attention scores (blocks 0..1023) + Wo2 f32->bf16 conversion
// (blocks 1024..7295). scores via factored tanh:
// tanh(m+d) = 1 - 2/(Em*Ed+1)  with Em=exp(2m), Ed=exp(2d) precomputed.
// ---------------------------------------------------------------------------
__global__ __launch_bounds__(256) void attn_conv(const float* __restrict__ Em,
                                                 const float* __restrict__ Ed,
                                                 const float* __restrict__ vw,
                                                 float* __restrict__ scores,
                                                 const float* __restrict__ Wo2,
                                                 unsigned short* __restrict__ Wo2_bf) {
    const int bid = blockIdx.x;
    const int tid = threadIdx.x;
    if (bid >= 1024) {
        int i = (bid - 1024) * 256 + tid;   // uint4 index, 1605632 total
        if (i < 1600000)
            reinterpret_cast<uint4*>(Wo2_bf)[i] = cvt8(Wo2 + (size_t)i * 8);
        else
            reinterpret_cast<uint4*>(Wo2_bf)[i] = make_uint4(0u, 0u, 0u, 0u);
        return;
    }
    __shared__ float ms[16][132];
    __shared__ float dsh[16][132];
    __shared__ float vs[128];
    const int t0 = (bid & 31) * 16, b0 = (bid >> 5) * 16;
    const int tl = tid & 15, bl = tid >> 4;
    float acc2 = 0.f, sv = 0.f;
    for (int d0 = 0; d0 < 512; d0 += 128) {
#pragma unroll
        for (int u = 0; u < 2; ++u) {
            int fi = tid + u * 256;
            int r = fi >> 5, c4 = fi & 31;
            *reinterpret_cast<float4*>(&ms[r][c4 * 4]) =
                *reinterpret_cast<const float4*>(&Em[(size_t)(t0 + r) * 512 + d0 + c4 * 4]);
            *reinterpret_cast<float4*>(&dsh[r][c4 * 4]) =
                *reinterpret_cast<const float4*>(&Ed[(size_t)(b0 + r) * 512 + d0 + c4 * 4]);
        }
        if (tid < 32)
            *reinterpret_cast<float4*>(&vs[tid * 4]) =
                *reinterpret_cast<const float4*>(&vw[d0 + tid * 4]);
        __syncthreads();
#pragma unroll 8
        for (int j = 0; j < 128; j += 4) {
            float4 mv = *reinterpret_cast<const float4*>(&ms[tl][j]);
            float4 dv = *reinterpret_cast<const float4*>(&dsh[bl][j]);
            float4 wv = *reinterpret_cast<const float4*>(&vs[j]);
            acc2 += wv.x * fast_rcp(__builtin_fmaf(mv.x, dv.x, 1.f));
            acc2 += wv.y * fast_rcp(__builtin_fmaf(mv.y, dv.y, 1.f));
            acc2 += wv.z * fast_rcp(__builtin_fmaf(mv.z, dv.z, 1.f));
            acc2 += wv.w * fast_rcp(__builtin_fmaf(mv.w, dv.w, 1.f));
            sv += wv.x + wv.y + wv.z + wv.w;
        }
        __syncthreads();
    }
    scores[(size_t)(b0 + bl) * 512 + (t0 + tl)] = sv - 2.f * acc2;
}

// ---------------------------------------------------------------------------
// Fused softmax + c_t. 64 blocks x 512 threads.
// ---------------------------------------------------------------------------
__global__ __launch_bounds__(512) void softmax_ct(const float* __restrict__ scores,
                                                  const float* __restrict__ mem,
                                                  float* __restrict__ attn_out,
                                                  float* __restrict__ ct_out,
                                                  unsigned short* __restrict__ hc_bf) {
    __shared__ float sl[8][512];
    const int tid = threadIdx.x;
    const int b0 = blockIdx.x * 8;
#pragma unroll
    for (int i = 0; i < 8; ++i) {
        int idx = tid + i * 512;
        int r = idx >> 9, c = idx & 511;
        sl[r][c] = scores[(size_t)(b0 + r) * 512 + c];
    }
    __syncthreads();
    {
        int r = tid >> 6, li = tid & 63;
        float mx = -1e30f;
#pragma unroll
        for (int k = 0; k < 8; ++k) mx = fmaxf(mx, sl[r][li + k * 64]);
#pragma unroll
        for (int m = 1; m < 64; m <<= 1) mx = fmaxf(mx, __shfl_xor(mx, m));
        float pv[8];
        float sum = 0.f;
#pragma unroll
        for (int k = 0; k < 8; ++k) {
            float p = __expf(sl[r][li + k * 64] - mx);
            pv[k] = p;
            sum += p;
        }
#pragma unroll
        for (int m = 1; m < 64; m <<= 1) sum += __shfl_xor(sum, m);
        float inv = 1.f / sum;
#pragma unroll
        for (int k = 0; k < 8; ++k) {
            float a = pv[k] * inv;
            sl[r][li + k * 64] = a;
            attn_out[(size_t)(b0 + r) * 512 + li + k * 64] = a;
        }
    }
    __syncthreads();
    const int d = tid;
    float acc[8] = {};
    for (int t = 0; t < 512; t += 2) {
        float m0v = mem[(size_t)t * 512 + d];
        float m1v = mem[(size_t)(t + 1) * 512 + d];
#pragma unroll
        for (int r = 0; r < 8; ++r) {
            acc[r] += sl[r][t] * m0v;
            acc[r] += sl[r][t + 1] * m1v;
        }
    }
#pragma unroll
    for (int r = 0; r < 8; ++r) {
        int b = b0 + r;
        ct_out[(size_t)b * 512 + d] = acc[r];
        hc_bf[(size_t)b * 768 + 256 + d] = (unsigned short)f2bf1(acc[r]);
    }
}

// ---------------------------------------------------------------------------
// Finish: fused {rowsum over ps + p_gen dot} -> scale bf16 exp-stash into
// f32 row + extra_zeros, coverage copy, scatter-add. 512 blocks x 1024 thr.
// ---------------------------------------------------------------------------
__global__ __launch_bounds__(1024) void finish_k(float* __restrict__ outF,
                                                 const float* __restrict__ ps,
                                                 const float* __restrict__ ct,
                                                 const float* __restrict__ scat,
                                                 const float* __restrict__ xw,
                                                 const float* __restrict__ Wpg,
                                                 const float* __restrict__ bpg,
                                                 float* __restrict__ outPG,
                                                 const float* __restrict__ ez,
                                                 const float* __restrict__ attn,
                                                 const int* __restrict__ ebev,
                                                 const float* __restrict__ cov,
                                                 float* __restrict__ outCov) {
    const int b = blockIdx.x;
    const int tid = threadIdx.x;
    __shared__ float sred[16], pgred[16], shsc[2];

    // --- fused rowsum + p_gen ---
    float sp = 0.f;
    if (tid < 2 * NCB_)
        sp = ps[(size_t)(tid >> 1) * 1024 + b * 2 + (tid & 1)];
    float pgp = 0.f;
    for (int idx = tid; idx < 1280; idx += 1024) {
        float wv = Wpg[idx];
        float xv;
        if (idx < 512) xv = ct[(size_t)b * 512 + idx];
        else if (idx < 1024) xv = scat[(size_t)b * 512 + idx - 512];
        else xv = xw[(size_t)b * 256 + idx - 1024];
        pgp += wv * xv;
    }
#pragma unroll
    for (int m = 1; m < 64; m <<= 1) {
        sp += __shfl_xor(sp, m);
        pgp += __shfl_xor(pgp, m);
    }
    if ((tid & 63) == 0) { sred[tid >> 6] = sp; pgred[tid >> 6] = pgp; }
    __syncthreads();
    if (tid == 0) {
        float s = 0.f, pg = 0.f;
#pragma unroll
        for (int i = 0; i < 16; ++i) { s += sred[i]; pg += pgred[i]; }
        float pgv = fast_sig(pg + bpg[0]);
        outPG[b] = pgv;
        shsc[0] = pgv / s;
        shsc[1] = 1.f - pgv;
    }
    __syncthreads();
    const float s = shsc[0];
    const float ad = shsc[1];

    // --- scale stash -> f32 row (in-place safe: read all, barrier, write) ---
    float* row = outF + (size_t)b * VE_;
    const unsigned short* el = (const unsigned short*)(row + ELOFF);
    uint2 buf[13];
    float4 ezbuf;
#pragma unroll
    for (int k = 0; k < 13; ++k) {
        int c4 = tid + (k << 10);
        if (c4 < 12500)
            buf[k] = *reinterpret_cast<const uint2*>(el + c4 * 4);
        else if (c4 < 12516)
            ezbuf = *reinterpret_cast<const float4*>(&ez[(size_t)b * NOOV_ + (c4 - 12500) * 4]);
    }
    __syncthreads();
#pragma unroll
    for (int k = 0; k < 13; ++k) {
        int c4 = tid + (k << 10);
        if (c4 < 12500) {
            uint2 e = buf[k];
            float4 v;
            v.x = __uint_as_float((e.x & 0xffffu) << 16) * s;
            v.y = __uint_as_float(e.x & 0xffff0000u) * s;
            v.z = __uint_as_float((e.y & 0xffffu) << 16) * s;
            v.w = __uint_as_float(e.y & 0xffff0000u) * s;
            *reinterpret_cast<float4*>(row + c4 * 4) = v;
        } else if (c4 < 12516) {
            *reinterpret_cast<float4*>(row + c4 * 4) = ezbuf;
        }
    }
    if (tid < 128)
        reinterpret_cast<float4*>(outCov + (size_t)b * 512)[tid] =
            reinterpret_cast<const float4*>(cov + (size_t)b * 512)[tid];
    __syncthreads();
    if (tid < 512) {
        int col = ebev[(size_t)b * 512 + tid];
        float val = ad * attn[(size_t)b * 512 + tid];
        atomicAdd(&row[col], val);
    }
}

// ---------------------------------------------------------------------------
extern "C" void kernel_launch(void* const* d_in, const int* in_sizes, int n_in,
                              void* d_out, int out_size, void* d_ws, size_t ws_size,
                              hipStream_t stream) {
    const int*   y    = (const int*)d_in[0];
    const float* h0   = (const float*)d_in[1];
    const float* c0   = (const float*)d_in[2];
    const float* ct1  = (const float*)d_in[3];
    const float* ez   = (const float*)d_in[4];
    const int*   ebev = (const int*)d_in[5];
    const float* cov  = (const float*)d_in[6];
    const float* emb  = (const float*)d_in[7];
    const float* Wx   = (const float*)d_in[8];
    const float* bx   = (const float*)d_in[9];
    const float* Wih  = (const float*)d_in[10];
    const float* Whh  = (const float*)d_in[11];
    const float* bih  = (const float*)d_in[12];
    const float* bhh  = (const float*)d_in[13];
    const float* memp = (const float*)d_in[14];
    const float* Wdp  = (const float*)d_in[15];
    const float* bdp  = (const float*)d_in[16];
    const float* vw   = (const float*)d_in[17];
    const float* Wpg  = (const float*)d_in[18];
    const float* bpg  = (const float*)d_in[19];
    const float* Wo1  = (const float*)d_in[20];
    const float* bo1  = (const float*)d_in[21];
    const float* Wo2  = (const float*)d_in[22];
    const float* bo2  = (const float*)d_in[23];

    float* out = (float*)d_out;
    const size_t OUT_FINAL = 0;
    const size_t OUT_H    = (size_t)B_ * VE_;
    const size_t OUT_C    = OUT_H + (size_t)B_ * H_;
    const size_t OUT_CT   = OUT_C + (size_t)B_ * H_;
    const size_t OUT_ATTN = OUT_CT + (size_t)B_ * 2 * H_;
    const size_t OUT_PG   = OUT_ATTN + (size_t)B_ * TK_;
    const size_t OUT_COV  = OUT_PG + B_;

    // ---- workspace layout ----
    char* wb = (char*)d_ws;
    float* xw     = (float*)wb;                       // 131072
    float* scat   = xw + 131072;                      // 262144
    float* Ed     = scat + 262144;                    // 262144
    float* scores = Ed + 262144;                      // 262144
    float* ps     = scores + 262144;                  // 400384
    float* Em     = ps + 400384;                      // 262144
    float* bsum   = Em + 262144;                      // 1024
    unsigned short* Wx_bf   = (unsigned short*)(bsum + 1024);
    unsigned short* Wcat_bf = Wx_bf + 196608;
    unsigned short* Wdp_bf  = Wcat_bf + 524288;
    unsigned short* Wo1_bf  = Wdp_bf + 262144;
    unsigned short* xcat_bf = Wo1_bf + 196608;
    unsigned short* xh_bf   = xcat_bf + 393216;
    unsigned short* scat_bf = xh_bf + 262144;
    unsigned short* hc_bf   = scat_bf + 262144;
    unsigned short* out1_bf = hc_bf + 393216;
    unsigned short* Wo2_bf  = out1_bf + 131072;       // 50176*256 ushorts

    // 0) small conversions / gathers (Wcat gate-interleaved, Em=exp(2*mem))
    prep_small<<<(PR_END + 255) / 256, 256, 0, stream>>>(
        Wx, Wdp, Wo1, Wih, Whh, bih, bhh, y, ct1, emb, h0, memp,
        Wx_bf, Wdp_bf, Wo1_bf, Wcat_bf, xcat_bf, xh_bf, Em, bsum);

    // 1) x = cat(c_t_1, emb[y]) @ Wx^T + bx  -> f32 xw + bf16 into xh_bf[:,0:256]
    gemm64<<<dim3(4, 8), 256, 0, stream>>>(xcat_bf, Wx_bf, bx, xw, xh_bf,
                                           256, 768, 512, 0, 0);

    // 2) LSTM gates GEMM + fused pointwise
    gemm_lstm<<<dim3(16, 8), 256, 0, stream>>>(xh_bf, Wcat_bf, bsum, c0,
                                               out + OUT_H, out + OUT_C,
                                               scat, scat_bf, hc_bf);

    // 3) attention: Ed = exp(2*(s_t_hat @ Wdp^T + bdp)) via mode=2 epilogue
    gemm64<<<dim3(8, 8), 256, 0, stream>>>(scat_bf, Wdp_bf, bdp, Ed, nullptr,
                                           512, 512, 0, 0, 2);
    attn_conv<<<7296, 256, 0, stream>>>(Em, Ed, vw, scores, Wo2, Wo2_bf);
    softmax_ct<<<64, 512, 0, stream>>>(scores, memp, out + OUT_ATTN,
                                       out + OUT_CT, hc_bf);

    // 4) vocab distribution: out1 -> exp-stash + partial sums
    gemm64<<<dim3(4, 8), 256, 0, stream>>>(hc_bf, Wo1_bf, bo1, nullptr, out1_bf,
                                           256, 768, 256, 0, 1);
    gemm_sum<<<1564, 1024, 0, stream>>>(out1_bf, Wo2_bf, bo2, out + OUT_FINAL, ps);

    // 5) finish: rowsum + p_gen + scale + extra_zeros + coverage + scatter
    finish_k<<<512, 1024, 0, stream>>>(out + OUT_FINAL, ps, out + OUT_CT, scat,
                                       xw, Wpg, bpg, out + OUT_PG, ez,
                                       out + OUT_ATTN, ebev, cov, out + OUT_COV);
}

// Round 11
// 206.736 us; speedup vs baseline: 1.0033x; 1.0033x over previous
//
#include <hip/hip_runtime.h>
#include <hip/hip_bf16.h>

// Problem constants
#define B_  512
#define H_  256
#define TK_ 512
#define V_  50000
#define NOOV_ 64
#define VE_ (V_ + NOOV_)   // 50064
#define NCB_ 391           // ceil(50000/128)
#define VPAD_ 50176        // 392*128, padded Wo2_bf rows
#define ELOFF 25032        // float offset of bf16 exp-stash inside each out row

typedef __bf16 bf16_t;
typedef __bf16 bf16x8 __attribute__((ext_vector_type(8)));
typedef float  f32x4  __attribute__((ext_vector_type(4)));

#define DEVI __device__ __forceinline__

DEVI float fast_rcp(float x) { return __builtin_amdgcn_rcpf(x); }
DEVI float fast_tanh(float x) {
    float e = __expf(2.f * x);
    return 1.f - 2.f * fast_rcp(e + 1.f);
}
DEVI float fast_sig(float x) { return fast_rcp(1.f + __expf(-x)); }

DEVI unsigned f2bf1(float f) {
    unsigned u = __float_as_uint(f);
    return (u + 0x7fffu + ((u >> 16) & 1u)) >> 16;   // RNE
}

DEVI uint4 cvt8(const float* p) {
    float4 a = *reinterpret_cast<const float4*>(p);
    float4 b = *reinterpret_cast<const float4*>(p + 4);
    bf16x8 v;
    v[0] = (__bf16)a.x; v[1] = (__bf16)a.y; v[2] = (__bf16)a.z; v[3] = (__bf16)a.w;
    v[4] = (__bf16)b.x; v[5] = (__bf16)b.y; v[6] = (__bf16)b.z; v[7] = (__bf16)b.w;
    return *reinterpret_cast<uint4*>(&v);
}

DEVI void gload_lds16(const void* g, void* l) {
    __builtin_amdgcn_global_load_lds(
        (const __attribute__((address_space(1))) void*)g,
        (__attribute__((address_space(3))) void*)l, 16, 0, 0);
}

// ---------------------------------------------------------------------------
// All small conversions / gathers in one kernel (uint4-granular items)
// Wcat gate-interleaved; also precomputes Em = exp(2*mem) for attn.
// ---------------------------------------------------------------------------
#define PR_O1 24576    // Wx end
#define PR_O2 57344    // Wdp end
#define PR_O3 81920    // Wo1 end
#define PR_O4 147456   // Wcat end
#define PR_O5 196608   // xcat end
#define PR_O6 212992   // xh-h0 end
#define PR_EM 245760   // Em end (32768 items of 8 floats)
#define PR_END 245888  // bsum end

__global__ __launch_bounds__(256) void prep_small(
        const float* __restrict__ Wx, const float* __restrict__ Wdp,
        const float* __restrict__ Wo1,
        const float* __restrict__ Wih, const float* __restrict__ Whh,
        const float* __restrict__ bih, const float* __restrict__ bhh,
        const int* __restrict__ y, const float* __restrict__ ct1,
        const float* __restrict__ emb, const float* __restrict__ h0,
        const float* __restrict__ mem,
        unsigned short* __restrict__ Wx_bf, unsigned short* __restrict__ Wdp_bf,
        unsigned short* __restrict__ Wo1_bf, unsigned short* __restrict__ Wcat_bf,
        unsigned short* __restrict__ xcat_bf, unsigned short* __restrict__ xh_bf,
        float* __restrict__ Em, float* __restrict__ bsum) {
    int idx = blockIdx.x * 256 + threadIdx.x;
    if (idx >= PR_END) return;
    if (idx < PR_O1) {
        reinterpret_cast<uint4*>(Wx_bf)[idx] = cvt8(Wx + (size_t)idx * 8);
    } else if (idx < PR_O2) {
        int i = idx - PR_O1;
        reinterpret_cast<uint4*>(Wdp_bf)[i] = cvt8(Wdp + (size_t)i * 8);
    } else if (idx < PR_O3) {
        int i = idx - PR_O2;
        reinterpret_cast<uint4*>(Wo1_bf)[i] = cvt8(Wo1 + (size_t)i * 8);
    } else if (idx < PR_O4) {
        int i = idx - PR_O3;
        int rp = i >> 6, c = (i & 63) * 8;
        int g = rp & 3, j = rp >> 2;
        const float* src = (c < 256) ? &Wih[(size_t)(g * 256 + j) * 256 + c]
                                     : &Whh[(size_t)(g * 256 + j) * 256 + (c - 256)];
        *reinterpret_cast<uint4*>(&Wcat_bf[(size_t)rp * 512 + c]) = cvt8(src);
    } else if (idx < PR_O5) {
        int i = idx - PR_O4;
        int b = i / 96, j = (i - b * 96) * 8;
        const float* src = (j < 512) ? &ct1[(size_t)b * 512 + j]
                                     : &emb[(size_t)y[b] * 256 + (j - 512)];
        *reinterpret_cast<uint4*>(&xcat_bf[(size_t)b * 768 + j]) = cvt8(src);
    } else if (idx < PR_O6) {
        int i = idx - PR_O5;
        int b = i >> 5, c = (i & 31) * 8;
        *reinterpret_cast<uint4*>(&xh_bf[(size_t)b * 512 + 256 + c]) =
            cvt8(&h0[(size_t)b * 256 + c]);
    } else if (idx < PR_EM) {
        int i = idx - PR_O6;
        const float* src = mem + (size_t)i * 8;
        float4 a = *reinterpret_cast<const float4*>(src);
        float4 b = *reinterpret_cast<const float4*>(src + 4);
        float4 ea, eb;
        ea.x = __expf(2.f * a.x); ea.y = __expf(2.f * a.y);
        ea.z = __expf(2.f * a.z); ea.w = __expf(2.f * a.w);
        eb.x = __expf(2.f * b.x); eb.y = __expf(2.f * b.y);
        eb.z = __expf(2.f * b.z); eb.w = __expf(2.f * b.w);
        *reinterpret_cast<float4*>(Em + (size_t)i * 8) = ea;
        *reinterpret_cast<float4*>(Em + (size_t)i * 8 + 4) = eb;
    } else {
        int g0 = (idx - PR_EM) * 8;
#pragma unroll
        for (int k = 0; k < 8; ++k) {
            int rp = g0 + k;
            int g = rp & 3, j = rp >> 2;
            bsum[rp] = bih[g * 256 + j] + bhh[g * 256 + j];
        }
    }
}

// ---------------------------------------------------------------------------
// Small GEMM: C[M,N] = A[M,K](bf16) * B[N,K]^T(bf16) + bias
// BM=BN=64, BK=64, 256 threads. mode: 0 none, 1 relu, 2 exp(2x) (Cf only).
// ---------------------------------------------------------------------------
__global__ __launch_bounds__(256) void gemm64(const unsigned short* __restrict__ Abf,
                                              const unsigned short* __restrict__ Bbf,
                                              const float* __restrict__ bias,
                                              float* __restrict__ Cf,
                                              unsigned short* __restrict__ Cb,
                                              int N, int K, int ldcb, int ocb,
                                              int mode) {
    __shared__ unsigned short As[2][4096];
    __shared__ unsigned short Bs[2][4096];
    const int tid = threadIdx.x;
    const int m0 = blockIdx.y * 64;
    const int n0 = blockIdx.x * 64;
    const int lane = tid & 63;
    const int wid = tid >> 6;
    const int wm = wid >> 1, wn = wid & 1;
    const int r16 = lane & 15, kq = lane >> 4;
    const int lrow = lane >> 3;               // 0..7
    const int lcol = (lane & 7) ^ lrow;       // swizzled source 16B-chunk
    const int ch0 = wid * 2;                  // 2 chunks/wave/matrix (8 total)

    f32x4 acc[2][2] = {};
    const int nt = K >> 6;

#define G64_STAGE(p, k0)                                                       \
    {                                                                          \
        _Pragma("unroll")                                                      \
        for (int i = 0; i < 2; ++i) {                                          \
            int ch = ch0 + i;                                                  \
            int row = ch * 8 + lrow;                                           \
            gload_lds16(&Abf[(size_t)(m0 + row) * K + (k0) + lcol * 8],        \
                        &As[p][ch * 512]);                                     \
            gload_lds16(&Bbf[(size_t)(n0 + row) * K + (k0) + lcol * 8],        \
                        &Bs[p][ch * 512]);                                     \
        }                                                                      \
    }

    G64_STAGE(0, 0);
    __syncthreads();
    int cur = 0;
    for (int t = 0; t < nt; ++t) {
        if (t + 1 < nt) G64_STAGE(cur ^ 1, (t + 1) << 6);
#pragma unroll
        for (int ks = 0; ks < 64; ks += 32) {
            int cbase = (ks >> 3) + kq;
            bf16x8 af[2], bfv[2];
#pragma unroll
            for (int mi = 0; mi < 2; ++mi) {
                int row = wm * 32 + mi * 16 + r16;
                af[mi] = *reinterpret_cast<const bf16x8*>(
                    &As[cur][row * 64 + (cbase ^ (row & 7)) * 8]);
            }
#pragma unroll
            for (int ni = 0; ni < 2; ++ni) {
                int row = wn * 32 + ni * 16 + r16;
                bfv[ni] = *reinterpret_cast<const bf16x8*>(
                    &Bs[cur][row * 64 + (cbase ^ (row & 7)) * 8]);
            }
#pragma unroll
            for (int mi = 0; mi < 2; ++mi)
#pragma unroll
                for (int ni = 0; ni < 2; ++ni)
                    acc[mi][ni] = __builtin_amdgcn_mfma_f32_16x16x32_bf16(af[mi], bfv[ni], acc[mi][ni], 0, 0, 0);
        }
        __syncthreads();
        cur ^= 1;
    }

#pragma unroll
    for (int mi = 0; mi < 2; ++mi)
#pragma unroll
        for (int ni = 0; ni < 2; ++ni) {
            int c = n0 + wn * 32 + ni * 16 + r16;
            float bv = bias[c];
#pragma unroll
            for (int r = 0; r < 4; ++r) {
                int rr = m0 + wm * 32 + mi * 16 + kq * 4 + r;
                float v = acc[mi][ni][r] + bv;
                if (mode == 1) v = fmaxf(v, 0.f);
                if (mode == 2) v = __expf(2.f * v);
                if (Cf) Cf[(size_t)rr * N + c] = v;
                if (Cb) Cb[(size_t)rr * ldcb + ocb + c] = (unsigned short)f2bf1(v);
            }
        }
}

// ---------------------------------------------------------------------------
// Gates GEMM + fused LSTM pointwise. (round-8 proven structure)
// ---------------------------------------------------------------------------
__global__ __launch_bounds__(256) void gemm_lstm(const unsigned short* __restrict__ Abf,
                                                 const unsigned short* __restrict__ Bbf,
                                                 const float* __restrict__ bsum,
                                                 const float* __restrict__ c0,
                                                 float* __restrict__ outH,
                                                 float* __restrict__ outC,
                                                 float* __restrict__ scat,
                                                 unsigned short* __restrict__ scat_bf,
                                                 unsigned short* __restrict__ hc_bf) {
    __shared__ unsigned short As[2][4096];
    __shared__ unsigned short Bs[2][4096];
    __shared__ float gsh[64][68];
    const int tid = threadIdx.x;
    const int m0 = blockIdx.y * 64;
    const int n0 = blockIdx.x * 64;
    const int lane = tid & 63;
    const int wid = tid >> 6;
    const int wm = wid >> 1, wn = wid & 1;
    const int r16 = lane & 15, kq = lane >> 4;
    const int lrow = lane >> 3;
    const int lcol = (lane & 7) ^ lrow;
    const int ch0 = wid * 2;

    f32x4 acc[2][2] = {};

#define GL_STAGE(p, k0)                                                        \
    {                                                                          \
        _Pragma("unroll")                                                      \
        for (int i = 0; i < 2; ++i) {                                          \
            int ch = ch0 + i;                                                  \
            int row = ch * 8 + lrow;                                           \
            gload_lds16(&Abf[(size_t)(m0 + row) * 512 + (k0) + lcol * 8],      \
                        &As[p][ch * 512]);                                     \
            gload_lds16(&Bbf[(size_t)(n0 + row) * 512 + (k0) + lcol * 8],      \
                        &Bs[p][ch * 512]);                                     \
        }                                                                      \
    }

    GL_STAGE(0, 0);
    __syncthreads();
    int cur = 0;
#pragma unroll
    for (int t = 0; t < 8; ++t) {
        if (t < 7) GL_STAGE(cur ^ 1, (t + 1) << 6);
#pragma unroll
        for (int ks = 0; ks < 64; ks += 32) {
            int cbase = (ks >> 3) + kq;
            bf16x8 af[2], bfv[2];
#pragma unroll
            for (int mi = 0; mi < 2; ++mi) {
                int row = wm * 32 + mi * 16 + r16;
                af[mi] = *reinterpret_cast<const bf16x8*>(
                    &As[cur][row * 64 + (cbase ^ (row & 7)) * 8]);
            }
#pragma unroll
            for (int ni = 0; ni < 2; ++ni) {
                int row = wn * 32 + ni * 16 + r16;
                bfv[ni] = *reinterpret_cast<const bf16x8*>(
                    &Bs[cur][row * 64 + (cbase ^ (row & 7)) * 8]);
            }
#pragma unroll
            for (int mi = 0; mi < 2; ++mi)
#pragma unroll
                for (int ni = 0; ni < 2; ++ni)
                    acc[mi][ni] = __builtin_amdgcn_mfma_f32_16x16x32_bf16(af[mi], bfv[ni], acc[mi][ni], 0, 0, 0);
        }
        __syncthreads();
        cur ^= 1;
    }

#pragma unroll
    for (int mi = 0; mi < 2; ++mi)
#pragma unroll
        for (int ni = 0; ni < 2; ++ni) {
            int cl = wn * 32 + ni * 16 + r16;
            float bv = bsum[n0 + cl];
#pragma unroll
            for (int r = 0; r < 4; ++r) {
                int rl = wm * 32 + mi * 16 + kq * 4 + r;
                gsh[rl][cl] = acc[mi][ni][r] + bv;
            }
        }
    __syncthreads();
    const int j0 = n0 >> 2;
#pragma unroll
    for (int u = tid; u < 1024; u += 256) {
        int bl = u >> 4, jl = u & 15;
        float4 g4 = *reinterpret_cast<const float4*>(&gsh[bl][jl * 4]);
        int b = m0 + bl, j = j0 + jl;
        float ig = fast_sig(g4.x);
        float fg = fast_sig(g4.y);
        float gg = fast_tanh(g4.z);
        float og = fast_sig(g4.w);
        float c = fg * c0[(size_t)b * 256 + j] + ig * gg;
        float h = og * fast_tanh(c);
        outH[(size_t)b * 256 + j] = h;
        outC[(size_t)b * 256 + j] = c;
        scat[(size_t)b * 512 + j] = h;
        scat[(size_t)b * 512 + 256 + j] = c;
        unsigned short hb = (unsigned short)f2bf1(h);
        unsigned short cbf = (unsigned short)f2bf1(c);
        scat_bf[(size_t)b * 512 + j] = hb;
        scat_bf[(size_t)b * 512 + 256 + j] = cbf;
        hc_bf[(size_t)b * 768 + j] = hb;
    }
}

// ---------------------------------------------------------------------------
// Vocab GEMM (round-9 dbuf structure, A moved from LDS to registers):
// A[row] fragments = 8 x bf16x8 (32 VGPR) loaded once from global (L2-hot,
// 256KB shared by all blocks). B staged via gload_lds, XOR-swizzled,
// double-buffered (32KB LDS), 1 barrier per K-tile. 1024 thr = 16 waves
// (8 wm x 2 wn), launch_bounds(1024,8) -> VGPR<=64 -> 2 blocks/CU.
// 1D grid 1564, XCD-swizzled so the 4 m-blocks of a cb share an XCD L2.
// ---------------------------------------------------------------------------
__global__ __launch_bounds__(1024, 8) void gemm_sum(const unsigned short* __restrict__ Abf,
                                                    const unsigned short* __restrict__ Bbf,
                                                    const float* __restrict__ bo2,
                                                    float* __restrict__ outF,
                                                    float* __restrict__ ps) {
    __shared__ unsigned short Bs[2][8192];
    const int f = blockIdx.x;
    int cb, mB;
    if (f < 1536) { cb = (f >> 5) * 8 + (f & 7); mB = (f >> 3) & 3; }
    else { int t = f - 1536; cb = 384 + t % 7; mB = t / 7; }
    const int tid = threadIdx.x;
    const int m0 = mB * 128;
    const int n0 = cb * 128;
    const int lane = tid & 63;
    const int wid = tid >> 6;                 // 0..15
    const int wm = wid >> 1, wn = wid & 1;    // 8 x 2
    const int r16 = lane & 15, kq = lane >> 4;
    const int lrow = lane >> 3;
    const int lcol = (lane & 7) ^ lrow;

#define GS_STAGE(p, k0)                                                        \
    {                                                                          \
        int row = wid * 8 + lrow;                                              \
        gload_lds16(&Bbf[(size_t)(n0 + row) * 256 + (k0) + lcol * 8],          \
                    &Bs[p][wid * 512]);                                        \
    }

    GS_STAGE(0, 0);

    // A fragments in registers: af[i] covers k-chunk i*4+kq (i = t*2 + ks/32)
    const unsigned short* aRow =
        Abf + (size_t)(m0 + wm * 16 + r16) * 256 + kq * 8;
    bf16x8 af[8];
#pragma unroll
    for (int i = 0; i < 8; ++i)
        af[i] = *reinterpret_cast<const bf16x8*>(aRow + i * 32);

    __syncthreads();

    f32x4 acc[4] = {};
    int cur = 0;
#pragma unroll
    for (int t = 0; t < 4; ++t) {
        if (t < 3) GS_STAGE(cur ^ 1, (t + 1) * 64);
#pragma unroll
        for (int ks = 0; ks < 64; ks += 32) {
            const int cbase = (ks >> 3) + kq;
            const bf16x8 a = af[t * 2 + (ks >> 5)];
#pragma unroll
            for (int ni = 0; ni < 4; ++ni) {
                int brow = wn * 64 + ni * 16 + r16;
                bf16x8 bv = *reinterpret_cast<const bf16x8*>(
                    &Bs[cur][brow * 64 + (cbase ^ (brow & 7)) * 8]);
                acc[ni] = __builtin_amdgcn_mfma_f32_16x16x32_bf16(a, bv, acc[ni], 0, 0, 0);
            }
        }
        __syncthreads();
        cur ^= 1;
    }

    float psum[4] = {0.f, 0.f, 0.f, 0.f};
#pragma unroll
    for (int ni = 0; ni < 4; ++ni) {
        int c = n0 + wn * 64 + ni * 16 + r16;
        bool ok = (c < V_);
        float bv = ok ? bo2[c] : 0.f;
#pragma unroll
        for (int r = 0; r < 4; ++r) {
            int rr = m0 + wm * 16 + kq * 4 + r;
            float p = __expf(acc[ni][r] + bv);
            unsigned eb = f2bf1(p);
            if (ok) {
                unsigned short* el =
                    (unsigned short*)(outF + (size_t)rr * VE_ + ELOFF);
                el[c] = (unsigned short)eb;
                psum[r] += __uint_as_float(eb << 16);
            }
        }
    }

#pragma unroll
    for (int r = 0; r < 4; ++r) {
        float v = psum[r];
        v += __shfl_xor(v, 1);
        v += __shfl_xor(v, 2);
        v += __shfl_xor(v, 4);
        v += __shfl_xor(v, 8);
        if (r16 == 0) {
            int rr = m0 + wm * 16 + kq * 4 + r;
            ps[((size_t)cb * 512 + rr) * 2 + wn] = v;
        }
    }
}

// ---------------------------------------------------------------------------
// Fused: attention scores (blocks 0..1023) + Wo2 f32->bf16 conversion
// (blocks 1024..7295). scores via factored tanh:
// tanh(m+d) = 1 - 2/(Em*Ed+1)  with Em=exp(2m), Ed=exp(2d) precomputed.
// ---------------------------------------------------------------------------
__global__ __launch_bounds__(256) void attn_conv(const float* __restrict__ Em,
                                                 const float* __restrict__ Ed,
                                                 const float* __restrict__ vw,
                                                 float* __restrict__ scores,
                                                 const float* __restrict__ Wo2,
                                                 unsigned short* __restrict__ Wo2_bf) {
    const int bid = blockIdx.x;
    const int tid = threadIdx.x;
    if (bid >= 1024) {
        int i = (bid - 1024) * 256 + tid;   // uint4 index, 1605632 total
        if (i < 1600000)
            reinterpret_cast<uint4*>(Wo2_bf)[i] = cvt8(Wo2 + (size_t)i * 8);
        else
            reinterpret_cast<uint4*>(Wo2_bf)[i] = make_uint4(0u, 0u, 0u, 0u);
        return;
    }
    __shared__ float ms[16][132];
    __shared__ float dsh[16][132];
    __shared__ float vs[128];
    const int t0 = (bid & 31) * 16, b0 = (bid >> 5) * 16;
    const int tl = tid & 15, bl = tid >> 4;
    float acc2 = 0.f, sv = 0.f;
    for (int d0 = 0; d0 < 512; d0 += 128) {
#pragma unroll
        for (int u = 0; u < 2; ++u) {
            int fi = tid + u * 256;
            int r = fi >> 5, c4 = fi & 31;
            *reinterpret_cast<float4*>(&ms[r][c4 * 4]) =
                *reinterpret_cast<const float4*>(&Em[(size_t)(t0 + r) * 512 + d0 + c4 * 4]);
            *reinterpret_cast<float4*>(&dsh[r][c4 * 4]) =
                *reinterpret_cast<const float4*>(&Ed[(size_t)(b0 + r) * 512 + d0 + c4 * 4]);
        }
        if (tid < 32)
            *reinterpret_cast<float4*>(&vs[tid * 4]) =
                *reinterpret_cast<const float4*>(&vw[d0 + tid * 4]);
        __syncthreads();
#pragma unroll 8
        for (int j = 0; j < 128; j += 4) {
            float4 mv = *reinterpret_cast<const float4*>(&ms[tl][j]);
            float4 dv = *reinterpret_cast<const float4*>(&dsh[bl][j]);
            float4 wv = *reinterpret_cast<const float4*>(&vs[j]);
            acc2 += wv.x * fast_rcp(__builtin_fmaf(mv.x, dv.x, 1.f));
            acc2 += wv.y * fast_rcp(__builtin_fmaf(mv.y, dv.y, 1.f));
            acc2 += wv.z * fast_rcp(__builtin_fmaf(mv.z, dv.z, 1.f));
            acc2 += wv.w * fast_rcp(__builtin_fmaf(mv.w, dv.w, 1.f));
            sv += wv.x + wv.y + wv.z + wv.w;
        }
        __syncthreads();
    }
    scores[(size_t)(b0 + bl) * 512 + (t0 + tl)] = sv - 2.f * acc2;
}

// ---------------------------------------------------------------------------
// Fused softmax + c_t. 64 blocks x 512 threads.
// ---------------------------------------------------------------------------
__global__ __launch_bounds__(512) void softmax_ct(const float* __restrict__ scores,
                                                  const float* __restrict__ mem,
                                                  float* __restrict__ attn_out,
                                                  float* __restrict__ ct_out,
                                                  unsigned short* __restrict__ hc_bf) {
    __shared__ float sl[8][512];
    const int tid = threadIdx.x;
    const int b0 = blockIdx.x * 8;
#pragma unroll
    for (int i = 0; i < 8; ++i) {
        int idx = tid + i * 512;
        int r = idx >> 9, c = idx & 511;
        sl[r][c] = scores[(size_t)(b0 + r) * 512 + c];
    }
    __syncthreads();
    {
        int r = tid >> 6, li = tid & 63;
        float mx = -1e30f;
#pragma unroll
        for (int k = 0; k < 8; ++k) mx = fmaxf(mx, sl[r][li + k * 64]);
#pragma unroll
        for (int m = 1; m < 64; m <<= 1) mx = fmaxf(mx, __shfl_xor(mx, m));
        float pv[8];
        float sum = 0.f;
#pragma unroll
        for (int k = 0; k < 8; ++k) {
            float p = __expf(sl[r][li + k * 64] - mx);
            pv[k] = p;
            sum += p;
        }
#pragma unroll
        for (int m = 1; m < 64; m <<= 1) sum += __shfl_xor(sum, m);
        float inv = 1.f / sum;
#pragma unroll
        for (int k = 0; k < 8; ++k) {
            float a = pv[k] * inv;
            sl[r][li + k * 64] = a;
            attn_out[(size_t)(b0 + r) * 512 + li + k * 64] = a;
        }
    }
    __syncthreads();
    const int d = tid;
    float acc[8] = {};
    for (int t = 0; t < 512; t += 2) {
        float m0v = mem[(size_t)t * 512 + d];
        float m1v = mem[(size_t)(t + 1) * 512 + d];
#pragma unroll
        for (int r = 0; r < 8; ++r) {
            acc[r] += sl[r][t] * m0v;
            acc[r] += sl[r][t + 1] * m1v;
        }
    }
#pragma unroll
    for (int r = 0; r < 8; ++r) {
        int b = b0 + r;
        ct_out[(size_t)b * 512 + d] = acc[r];
        hc_bf[(size_t)b * 768 + 256 + d] = (unsigned short)f2bf1(acc[r]);
    }
}

// ---------------------------------------------------------------------------
// Finish: fused {rowsum over ps + p_gen dot} -> scale bf16 exp-stash into
// f32 row + extra_zeros, coverage copy, scatter-add. 512 blocks x 1024 thr.
// ---------------------------------------------------------------------------
__global__ __launch_bounds__(1024) void finish_k(float* __restrict__ outF,
                                                 const float* __restrict__ ps,
                                                 const float* __restrict__ ct,
                                                 const float* __restrict__ scat,
                                                 const float* __restrict__ xw,
                                                 const float* __restrict__ Wpg,
                                                 const float* __restrict__ bpg,
                                                 float* __restrict__ outPG,
                                                 const float* __restrict__ ez,
                                                 const float* __restrict__ attn,
                                                 const int* __restrict__ ebev,
                                                 const float* __restrict__ cov,
                                                 float* __restrict__ outCov) {
    const int b = blockIdx.x;
    const int tid = threadIdx.x;
    __shared__ float sred[16], pgred[16], shsc[2];

    // --- fused rowsum + p_gen ---
    float sp = 0.f;
    if (tid < 2 * NCB_)
        sp = ps[(size_t)(tid >> 1) * 1024 + b * 2 + (tid & 1)];
    float pgp = 0.f;
    for (int idx = tid; idx < 1280; idx += 1024) {
        float wv = Wpg[idx];
        float xv;
        if (idx < 512) xv = ct[(size_t)b * 512 + idx];
        else if (idx < 1024) xv = scat[(size_t)b * 512 + idx - 512];
        else xv = xw[(size_t)b * 256 + idx - 1024];
        pgp += wv * xv;
    }
#pragma unroll
    for (int m = 1; m < 64; m <<= 1) {
        sp += __shfl_xor(sp, m);
        pgp += __shfl_xor(pgp, m);
    }
    if ((tid & 63) == 0) { sred[tid >> 6] = sp; pgred[tid >> 6] = pgp; }
    __syncthreads();
    if (tid == 0) {
        float s = 0.f, pg = 0.f;
#pragma unroll
        for (int i = 0; i < 16; ++i) { s += sred[i]; pg += pgred[i]; }
        float pgv = fast_sig(pg + bpg[0]);
        outPG[b] = pgv;
        shsc[0] = pgv / s;
        shsc[1] = 1.f - pgv;
    }
    __syncthreads();
    const float s = shsc[0];
    const float ad = shsc[1];

    // --- scale stash -> f32 row (in-place safe: read all, barrier, write) ---
    float* row = outF + (size_t)b * VE_;
    const unsigned short* el = (const unsigned short*)(row + ELOFF);
    uint2 buf[13];
    float4 ezbuf;
#pragma unroll
    for (int k = 0; k < 13; ++k) {
        int c4 = tid + (k << 10);
        if (c4 < 12500)
            buf[k] = *reinterpret_cast<const uint2*>(el + c4 * 4);
        else if (c4 < 12516)
            ezbuf = *reinterpret_cast<const float4*>(&ez[(size_t)b * NOOV_ + (c4 - 12500) * 4]);
    }
    __syncthreads();
#pragma unroll
    for (int k = 0; k < 13; ++k) {
        int c4 = tid + (k << 10);
        if (c4 < 12500) {
            uint2 e = buf[k];
            float4 v;
            v.x = __uint_as_float((e.x & 0xffffu) << 16) * s;
            v.y = __uint_as_float(e.x & 0xffff0000u) * s;
            v.z = __uint_as_float((e.y & 0xffffu) << 16) * s;
            v.w = __uint_as_float(e.y & 0xffff0000u) * s;
            *reinterpret_cast<float4*>(row + c4 * 4) = v;
        } else if (c4 < 12516) {
            *reinterpret_cast<float4*>(row + c4 * 4) = ezbuf;
        }
    }
    if (tid < 128)
        reinterpret_cast<float4*>(outCov + (size_t)b * 512)[tid] =
            reinterpret_cast<const float4*>(cov + (size_t)b * 512)[tid];
    __syncthreads();
    if (tid < 512) {
        int col = ebev[(size_t)b * 512 + tid];
        float val = ad * attn[(size_t)b * 512 + tid];
        atomicAdd(&row[col], val);
    }
}

// ---------------------------------------------------------------------------
extern "C" void kernel_launch(void* const* d_in, const int* in_sizes, int n_in,
                              void* d_out, int out_size, void* d_ws, size_t ws_size,
                              hipStream_t stream) {
    const int*   y    = (const int*)d_in[0];
    const float* h0   = (const float*)d_in[1];
    const float* c0   = (const float*)d_in[2];
    const float* ct1  = (const float*)d_in[3];
    const float* ez   = (const float*)d_in[4];
    const int*   ebev = (const int*)d_in[5];
    const float* cov  = (const float*)d_in[6];
    const float* emb  = (const float*)d_in[7];
    const float* Wx   = (const float*)d_in[8];
    const float* bx   = (const float*)d_in[9];
    const float* Wih  = (const float*)d_in[10];
    const float* Whh  = (const float*)d_in[11];
    const float* bih  = (const float*)d_in[12];
    const float* bhh  = (const float*)d_in[13];
    const float* memp = (const float*)d_in[14];
    const float* Wdp  = (const float*)d_in[15];
    const float* bdp  = (const float*)d_in[16];
    const float* vw   = (const float*)d_in[17];
    const float* Wpg  = (const float*)d_in[18];
    const float* bpg  = (const float*)d_in[19];
    const float* Wo1  = (const float*)d_in[20];
    const float* bo1  = (const float*)d_in[21];
    const float* Wo2  = (const float*)d_in[22];
    const float* bo2  = (const float*)d_in[23];

    float* out = (float*)d_out;
    const size_t OUT_FINAL = 0;
    const size_t OUT_H    = (size_t)B_ * VE_;
    const size_t OUT_C    = OUT_H + (size_t)B_ * H_;
    const size_t OUT_CT   = OUT_C + (size_t)B_ * H_;
    const size_t OUT_ATTN = OUT_CT + (size_t)B_ * 2 * H_;
    const size_t OUT_PG   = OUT_ATTN + (size_t)B_ * TK_;
    const size_t OUT_COV  = OUT_PG + B_;

    // ---- workspace layout ----
    char* wb = (char*)d_ws;
    float* xw     = (float*)wb;                       // 131072
    float* scat   = xw + 131072;                      // 262144
    float* Ed     = scat + 262144;                    // 262144
    float* scores = Ed + 262144;                      // 262144
    float* ps     = scores + 262144;                  // 400384
    float* Em     = ps + 400384;                      // 262144
    float* bsum   = Em + 262144;                      // 1024
    unsigned short* Wx_bf   = (unsigned short*)(bsum + 1024);
    unsigned short* Wcat_bf = Wx_bf + 196608;
    unsigned short* Wdp_bf  = Wcat_bf + 524288;
    unsigned short* Wo1_bf  = Wdp_bf + 262144;
    unsigned short* xcat_bf = Wo1_bf + 196608;
    unsigned short* xh_bf   = xcat_bf + 393216;
    unsigned short* scat_bf = xh_bf + 262144;
    unsigned short* hc_bf   = scat_bf + 262144;
    unsigned short* out1_bf = hc_bf + 393216;
    unsigned short* Wo2_bf  = out1_bf + 131072;       // 50176*256 ushorts

    // 0) small conversions / gathers (Wcat gate-interleaved, Em=exp(2*mem))
    prep_small<<<(PR_END + 255) / 256, 256, 0, stream>>>(
        Wx, Wdp, Wo1, Wih, Whh, bih, bhh, y, ct1, emb, h0, memp,
        Wx_bf, Wdp_bf, Wo1_bf, Wcat_bf, xcat_bf, xh_bf, Em, bsum);

    // 1) x = cat(c_t_1, emb[y]) @ Wx^T + bx  -> f32 xw + bf16 into xh_bf[:,0:256]
    gemm64<<<dim3(4, 8), 256, 0, stream>>>(xcat_bf, Wx_bf, bx, xw, xh_bf,
                                           256, 768, 512, 0, 0);

    // 2) LSTM gates GEMM + fused pointwise
    gemm_lstm<<<dim3(16, 8), 256, 0, stream>>>(xh_bf, Wcat_bf, bsum, c0,
                                               out + OUT_H, out + OUT_C,
                                               scat, scat_bf, hc_bf);

    // 3) attention: Ed = exp(2*(s_t_hat @ Wdp^T + bdp)) via mode=2 epilogue
    gemm64<<<dim3(8, 8), 256, 0, stream>>>(scat_bf, Wdp_bf, bdp, Ed, nullptr,
                                           512, 512, 0, 0, 2);
    attn_conv<<<7296, 256, 0, stream>>>(Em, Ed, vw, scores, Wo2, Wo2_bf);
    softmax_ct<<<64, 512, 0, stream>>>(scores, memp, out + OUT_ATTN,
                                       out + OUT_CT, hc_bf);

    // 4) vocab distribution: out1 -> exp-stash + partial sums
    gemm64<<<dim3(4, 8), 256, 0, stream>>>(hc_bf, Wo1_bf, bo1, nullptr, out1_bf,
                                           256, 768, 256, 0, 1);
    gemm_sum<<<1564, 1024, 0, stream>>>(out1_bf, Wo2_bf, bo2, out + OUT_FINAL, ps);

    // 5) finish: rowsum + p_gen + scale + extra_zeros + coverage + scatter
    finish_k<<<512, 1024, 0, stream>>>(out + OUT_FINAL, ps, out + OUT_CT, scat,
                                       xw, Wpg, bpg, out + OUT_PG, ez,
                                       out + OUT_ATTN, ebev, cov, out + OUT_COV);
}

// Round 12
// 189.260 us; speedup vs baseline: 1.0960x; 1.0923x over previous
//
#include <hip/hip_runtime.h>
#include <hip/hip_bf16.h>

// Problem constants
#define B_  512
#define H_  256
#define TK_ 512
#define V_  50000
#define NOOV_ 64
#define VE_ (V_ + NOOV_)   // 50064
#define NCB_ 391           // ceil(50000/128)
#define VPAD_ 50176        // 392*128, padded Wo2_bf rows
#define ELOFF 25032        // float offset of bf16 exp-stash inside each out row

typedef __bf16 bf16_t;
typedef __bf16 bf16x8 __attribute__((ext_vector_type(8)));
typedef float  f32x4  __attribute__((ext_vector_type(4)));

#define DEVI __device__ __forceinline__

DEVI float fast_rcp(float x) { return __builtin_amdgcn_rcpf(x); }
DEVI float fast_tanh(float x) {
    float e = __expf(2.f * x);
    return 1.f - 2.f * fast_rcp(e + 1.f);
}
DEVI float fast_sig(float x) { return fast_rcp(1.f + __expf(-x)); }

DEVI unsigned f2bf1(float f) {
    unsigned u = __float_as_uint(f);
    return (u + 0x7fffu + ((u >> 16) & 1u)) >> 16;   // RNE
}

DEVI uint4 cvt8(const float* p) {
    float4 a = *reinterpret_cast<const float4*>(p);
    float4 b = *reinterpret_cast<const float4*>(p + 4);
    bf16x8 v;
    v[0] = (__bf16)a.x; v[1] = (__bf16)a.y; v[2] = (__bf16)a.z; v[3] = (__bf16)a.w;
    v[4] = (__bf16)b.x; v[5] = (__bf16)b.y; v[6] = (__bf16)b.z; v[7] = (__bf16)b.w;
    return *reinterpret_cast<uint4*>(&v);
}

DEVI void gload_lds16(const void* g, void* l) {
    __builtin_amdgcn_global_load_lds(
        (const __attribute__((address_space(1))) void*)g,
        (__attribute__((address_space(3))) void*)l, 16, 0, 0);
}

// ---------------------------------------------------------------------------
// All small conversions / gathers in one kernel (uint4-granular items)
// Wcat gate-interleaved; also precomputes Em = exp(2*mem) for attn.
// ---------------------------------------------------------------------------
#define PR_O1 24576    // Wx end
#define PR_O2 57344    // Wdp end
#define PR_O3 81920    // Wo1 end
#define PR_O4 147456   // Wcat end
#define PR_O5 196608   // xcat end
#define PR_O6 212992   // xh-h0 end
#define PR_EM 245760   // Em end (32768 items of 8 floats)
#define PR_END 245888  // bsum end

__global__ __launch_bounds__(256) void prep_small(
        const float* __restrict__ Wx, const float* __restrict__ Wdp,
        const float* __restrict__ Wo1,
        const float* __restrict__ Wih, const float* __restrict__ Whh,
        const float* __restrict__ bih, const float* __restrict__ bhh,
        const int* __restrict__ y, const float* __restrict__ ct1,
        const float* __restrict__ emb, const float* __restrict__ h0,
        const float* __restrict__ mem,
        unsigned short* __restrict__ Wx_bf, unsigned short* __restrict__ Wdp_bf,
        unsigned short* __restrict__ Wo1_bf, unsigned short* __restrict__ Wcat_bf,
        unsigned short* __restrict__ xcat_bf, unsigned short* __restrict__ xh_bf,
        float* __restrict__ Em, float* __restrict__ bsum) {
    int idx = blockIdx.x * 256 + threadIdx.x;
    if (idx >= PR_END) return;
    if (idx < PR_O1) {
        reinterpret_cast<uint4*>(Wx_bf)[idx] = cvt8(Wx + (size_t)idx * 8);
    } else if (idx < PR_O2) {
        int i = idx - PR_O1;
        reinterpret_cast<uint4*>(Wdp_bf)[i] = cvt8(Wdp + (size_t)i * 8);
    } else if (idx < PR_O3) {
        int i = idx - PR_O2;
        reinterpret_cast<uint4*>(Wo1_bf)[i] = cvt8(Wo1 + (size_t)i * 8);
    } else if (idx < PR_O4) {
        int i = idx - PR_O3;
        int rp = i >> 6, c = (i & 63) * 8;
        int g = rp & 3, j = rp >> 2;
        const float* src = (c < 256) ? &Wih[(size_t)(g * 256 + j) * 256 + c]
                                     : &Whh[(size_t)(g * 256 + j) * 256 + (c - 256)];
        *reinterpret_cast<uint4*>(&Wcat_bf[(size_t)rp * 512 + c]) = cvt8(src);
    } else if (idx < PR_O5) {
        int i = idx - PR_O4;
        int b = i / 96, j = (i - b * 96) * 8;
        const float* src = (j < 512) ? &ct1[(size_t)b * 512 + j]
                                     : &emb[(size_t)y[b] * 256 + (j - 512)];
        *reinterpret_cast<uint4*>(&xcat_bf[(size_t)b * 768 + j]) = cvt8(src);
    } else if (idx < PR_O6) {
        int i = idx - PR_O5;
        int b = i >> 5, c = (i & 31) * 8;
        *reinterpret_cast<uint4*>(&xh_bf[(size_t)b * 512 + 256 + c]) =
            cvt8(&h0[(size_t)b * 256 + c]);
    } else if (idx < PR_EM) {
        int i = idx - PR_O6;
        const float* src = mem + (size_t)i * 8;
        float4 a = *reinterpret_cast<const float4*>(src);
        float4 b = *reinterpret_cast<const float4*>(src + 4);
        float4 ea, eb;
        ea.x = __expf(2.f * a.x); ea.y = __expf(2.f * a.y);
        ea.z = __expf(2.f * a.z); ea.w = __expf(2.f * a.w);
        eb.x = __expf(2.f * b.x); eb.y = __expf(2.f * b.y);
        eb.z = __expf(2.f * b.z); eb.w = __expf(2.f * b.w);
        *reinterpret_cast<float4*>(Em + (size_t)i * 8) = ea;
        *reinterpret_cast<float4*>(Em + (size_t)i * 8 + 4) = eb;
    } else {
        int g0 = (idx - PR_EM) * 8;
#pragma unroll
        for (int k = 0; k < 8; ++k) {
            int rp = g0 + k;
            int g = rp & 3, j = rp >> 2;
            bsum[rp] = bih[g * 256 + j] + bhh[g * 256 + j];
        }
    }
}

// ---------------------------------------------------------------------------
// Small GEMM: C[M,N] = A[M,K](bf16) * B[N,K]^T(bf16) + bias
// BM=BN=64, BK=64, 256 threads. mode: 0 none, 1 relu, 2 exp(2x) (Cf only).
// ---------------------------------------------------------------------------
__global__ __launch_bounds__(256) void gemm64(const unsigned short* __restrict__ Abf,
                                              const unsigned short* __restrict__ Bbf,
                                              const float* __restrict__ bias,
                                              float* __restrict__ Cf,
                                              unsigned short* __restrict__ Cb,
                                              int N, int K, int ldcb, int ocb,
                                              int mode) {
    __shared__ unsigned short As[2][4096];
    __shared__ unsigned short Bs[2][4096];
    const int tid = threadIdx.x;
    const int m0 = blockIdx.y * 64;
    const int n0 = blockIdx.x * 64;
    const int lane = tid & 63;
    const int wid = tid >> 6;
    const int wm = wid >> 1, wn = wid & 1;
    const int r16 = lane & 15, kq = lane >> 4;
    const int lrow = lane >> 3;               // 0..7
    const int lcol = (lane & 7) ^ lrow;       // swizzled source 16B-chunk
    const int ch0 = wid * 2;                  // 2 chunks/wave/matrix (8 total)

    f32x4 acc[2][2] = {};
    const int nt = K >> 6;

#define G64_STAGE(p, k0)                                                       \
    {                                                                          \
        _Pragma("unroll")                                                      \
        for (int i = 0; i < 2; ++i) {                                          \
            int ch = ch0 + i;                                                  \
            int row = ch * 8 + lrow;                                           \
            gload_lds16(&Abf[(size_t)(m0 + row) * K + (k0) + lcol * 8],        \
                        &As[p][ch * 512]);                                     \
            gload_lds16(&Bbf[(size_t)(n0 + row) * K + (k0) + lcol * 8],        \
                        &Bs[p][ch * 512]);                                     \
        }                                                                      \
    }

    G64_STAGE(0, 0);
    __syncthreads();
    int cur = 0;
    for (int t = 0; t < nt; ++t) {
        if (t + 1 < nt) G64_STAGE(cur ^ 1, (t + 1) << 6);
#pragma unroll
        for (int ks = 0; ks < 64; ks += 32) {
            int cbase = (ks >> 3) + kq;
            bf16x8 af[2], bfv[2];
#pragma unroll
            for (int mi = 0; mi < 2; ++mi) {
                int row = wm * 32 + mi * 16 + r16;
                af[mi] = *reinterpret_cast<const bf16x8*>(
                    &As[cur][row * 64 + (cbase ^ (row & 7)) * 8]);
            }
#pragma unroll
            for (int ni = 0; ni < 2; ++ni) {
                int row = wn * 32 + ni * 16 + r16;
                bfv[ni] = *reinterpret_cast<const bf16x8*>(
                    &Bs[cur][row * 64 + (cbase ^ (row & 7)) * 8]);
            }
#pragma unroll
            for (int mi = 0; mi < 2; ++mi)
#pragma unroll
                for (int ni = 0; ni < 2; ++ni)
                    acc[mi][ni] = __builtin_amdgcn_mfma_f32_16x16x32_bf16(af[mi], bfv[ni], acc[mi][ni], 0, 0, 0);
        }
        __syncthreads();
        cur ^= 1;
    }

#pragma unroll
    for (int mi = 0; mi < 2; ++mi)
#pragma unroll
        for (int ni = 0; ni < 2; ++ni) {
            int c = n0 + wn * 32 + ni * 16 + r16;
            float bv = bias[c];
#pragma unroll
            for (int r = 0; r < 4; ++r) {
                int rr = m0 + wm * 32 + mi * 16 + kq * 4 + r;
                float v = acc[mi][ni][r] + bv;
                if (mode == 1) v = fmaxf(v, 0.f);
                if (mode == 2) v = __expf(2.f * v);
                if (Cf) Cf[(size_t)rr * N + c] = v;
                if (Cb) Cb[(size_t)rr * ldcb + ocb + c] = (unsigned short)f2bf1(v);
            }
        }
}

// ---------------------------------------------------------------------------
// Gates GEMM + fused LSTM pointwise. (round-8 proven structure)
// ---------------------------------------------------------------------------
__global__ __launch_bounds__(256) void gemm_lstm(const unsigned short* __restrict__ Abf,
                                                 const unsigned short* __restrict__ Bbf,
                                                 const float* __restrict__ bsum,
                                                 const float* __restrict__ c0,
                                                 float* __restrict__ outH,
                                                 float* __restrict__ outC,
                                                 float* __restrict__ scat,
                                                 unsigned short* __restrict__ scat_bf,
                                                 unsigned short* __restrict__ hc_bf) {
    __shared__ unsigned short As[2][4096];
    __shared__ unsigned short Bs[2][4096];
    __shared__ float gsh[64][68];
    const int tid = threadIdx.x;
    const int m0 = blockIdx.y * 64;
    const int n0 = blockIdx.x * 64;
    const int lane = tid & 63;
    const int wid = tid >> 6;
    const int wm = wid >> 1, wn = wid & 1;
    const int r16 = lane & 15, kq = lane >> 4;
    const int lrow = lane >> 3;
    const int lcol = (lane & 7) ^ lrow;
    const int ch0 = wid * 2;

    f32x4 acc[2][2] = {};

#define GL_STAGE(p, k0)                                                        \
    {                                                                          \
        _Pragma("unroll")                                                      \
        for (int i = 0; i < 2; ++i) {                                          \
            int ch = ch0 + i;                                                  \
            int row = ch * 8 + lrow;                                           \
            gload_lds16(&Abf[(size_t)(m0 + row) * 512 + (k0) + lcol * 8],      \
                        &As[p][ch * 512]);                                     \
            gload_lds16(&Bbf[(size_t)(n0 + row) * 512 + (k0) + lcol * 8],      \
                        &Bs[p][ch * 512]);                                     \
        }                                                                      \
    }

    GL_STAGE(0, 0);
    __syncthreads();
    int cur = 0;
#pragma unroll
    for (int t = 0; t < 8; ++t) {
        if (t < 7) GL_STAGE(cur ^ 1, (t + 1) << 6);
#pragma unroll
        for (int ks = 0; ks < 64; ks += 32) {
            int cbase = (ks >> 3) + kq;
            bf16x8 af[2], bfv[2];
#pragma unroll
            for (int mi = 0; mi < 2; ++mi) {
                int row = wm * 32 + mi * 16 + r16;
                af[mi] = *reinterpret_cast<const bf16x8*>(
                    &As[cur][row * 64 + (cbase ^ (row & 7)) * 8]);
            }
#pragma unroll
            for (int ni = 0; ni < 2; ++ni) {
                int row = wn * 32 + ni * 16 + r16;
                bfv[ni] = *reinterpret_cast<const bf16x8*>(
                    &Bs[cur][row * 64 + (cbase ^ (row & 7)) * 8]);
            }
#pragma unroll
            for (int mi = 0; mi < 2; ++mi)
#pragma unroll
                for (int ni = 0; ni < 2; ++ni)
                    acc[mi][ni] = __builtin_amdgcn_mfma_f32_16x16x32_bf16(af[mi], bfv[ni], acc[mi][ni], 0, 0, 0);
        }
        __syncthreads();
        cur ^= 1;
    }

#pragma unroll
    for (int mi = 0; mi < 2; ++mi)
#pragma unroll
        for (int ni = 0; ni < 2; ++ni) {
            int cl = wn * 32 + ni * 16 + r16;
            float bv = bsum[n0 + cl];
#pragma unroll
            for (int r = 0; r < 4; ++r) {
                int rl = wm * 32 + mi * 16 + kq * 4 + r;
                gsh[rl][cl] = acc[mi][ni][r] + bv;
            }
        }
    __syncthreads();
    const int j0 = n0 >> 2;
#pragma unroll
    for (int u = tid; u < 1024; u += 256) {
        int bl = u >> 4, jl = u & 15;
        float4 g4 = *reinterpret_cast<const float4*>(&gsh[bl][jl * 4]);
        int b = m0 + bl, j = j0 + jl;
        float ig = fast_sig(g4.x);
        float fg = fast_sig(g4.y);
        float gg = fast_tanh(g4.z);
        float og = fast_sig(g4.w);
        float c = fg * c0[(size_t)b * 256 + j] + ig * gg;
        float h = og * fast_tanh(c);
        outH[(size_t)b * 256 + j] = h;
        outC[(size_t)b * 256 + j] = c;
        scat[(size_t)b * 512 + j] = h;
        scat[(size_t)b * 512 + 256 + j] = c;
        unsigned short hb = (unsigned short)f2bf1(h);
        unsigned short cbf = (unsigned short)f2bf1(c);
        scat_bf[(size_t)b * 512 + j] = hb;
        scat_bf[(size_t)b * 512 + 256 + j] = cbf;
        hc_bf[(size_t)b * 768 + j] = hb;
    }
}

// ---------------------------------------------------------------------------
// Vocab GEMM (round-8 proven structure, restored): 1024 threads = 16 waves
// (8 wm x 2 wn), each wave one 16x128 output strip (1 mi x 4 ni). A+B both
// staged via gload_lds, XOR-swizzled, double-buffered (64KB LDS), 1 barrier
// per K-tile. launch_bounds(1024,8) keeps VGPR low -> 2 blocks/CU.
// ps written TRANSPOSED: ps[rr*782 + cb*2 + wn] so finish_k reads coalesced.
// 1D grid 1564, XCD-swizzled so the 4 m-blocks of a cb share an XCD L2.
// ---------------------------------------------------------------------------
__global__ __launch_bounds__(1024, 8) void gemm_sum(const unsigned short* __restrict__ Abf,
                                                    const unsigned short* __restrict__ Bbf,
                                                    const float* __restrict__ bo2,
                                                    float* __restrict__ outF,
                                                    float* __restrict__ ps) {
    __shared__ unsigned short As[2][8192];
    __shared__ unsigned short Bs[2][8192];
    const int f = blockIdx.x;
    int cb, mB;
    if (f < 1536) { cb = (f >> 5) * 8 + (f & 7); mB = (f >> 3) & 3; }
    else { int t = f - 1536; cb = 384 + t % 7; mB = t / 7; }
    const int tid = threadIdx.x;
    const int m0 = mB * 128;
    const int n0 = cb * 128;
    const int lane = tid & 63;
    const int wid = tid >> 6;                 // 0..15
    const int wm = wid >> 1, wn = wid & 1;    // 8 x 2
    const int r16 = lane & 15, kq = lane >> 4;
    const int lrow = lane >> 3;
    const int lcol = (lane & 7) ^ lrow;

#define GS_STAGE(p, k0)                                                        \
    {                                                                          \
        int row = wid * 8 + lrow;                                              \
        gload_lds16(&Abf[(size_t)(m0 + row) * 256 + (k0) + lcol * 8],          \
                    &As[p][wid * 512]);                                        \
        gload_lds16(&Bbf[(size_t)(n0 + row) * 256 + (k0) + lcol * 8],          \
                    &Bs[p][wid * 512]);                                        \
    }

    GS_STAGE(0, 0);
    __syncthreads();
    f32x4 acc[4] = {};
    int cur = 0;
#pragma unroll
    for (int t = 0; t < 4; ++t) {
        if (t < 3) GS_STAGE(cur ^ 1, (t + 1) * 64);
#pragma unroll
        for (int ks = 0; ks < 64; ks += 32) {
            const int cbase = (ks >> 3) + kq;
            const int arow = wm * 16 + r16;
            bf16x8 af = *reinterpret_cast<const bf16x8*>(
                &As[cur][arow * 64 + (cbase ^ (arow & 7)) * 8]);
#pragma unroll
            for (int ni = 0; ni < 4; ++ni) {
                int brow = wn * 64 + ni * 16 + r16;
                bf16x8 bv = *reinterpret_cast<const bf16x8*>(
                    &Bs[cur][brow * 64 + (cbase ^ (brow & 7)) * 8]);
                acc[ni] = __builtin_amdgcn_mfma_f32_16x16x32_bf16(af, bv, acc[ni], 0, 0, 0);
            }
        }
        __syncthreads();
        cur ^= 1;
    }

    float psum[4] = {0.f, 0.f, 0.f, 0.f};
#pragma unroll
    for (int ni = 0; ni < 4; ++ni) {
        int c = n0 + wn * 64 + ni * 16 + r16;
        bool ok = (c < V_);
        float bv = ok ? bo2[c] : 0.f;
#pragma unroll
        for (int r = 0; r < 4; ++r) {
            int rr = m0 + wm * 16 + kq * 4 + r;
            float p = __expf(acc[ni][r] + bv);
            unsigned eb = f2bf1(p);
            if (ok) {
                unsigned short* el =
                    (unsigned short*)(outF + (size_t)rr * VE_ + ELOFF);
                el[c] = (unsigned short)eb;
                psum[r] += __uint_as_float(eb << 16);
            }
        }
    }

#pragma unroll
    for (int r = 0; r < 4; ++r) {
        float v = psum[r];
        v += __shfl_xor(v, 1);
        v += __shfl_xor(v, 2);
        v += __shfl_xor(v, 4);
        v += __shfl_xor(v, 8);
        if (r16 == 0) {
            int rr = m0 + wm * 16 + kq * 4 + r;
            ps[(size_t)rr * (2 * NCB_) + cb * 2 + wn] = v;
        }
    }
}

// ---------------------------------------------------------------------------
// Fused: attention scores (blocks 0..1023) + Wo2 f32->bf16 conversion
// (blocks 1024..7295). scores via factored tanh:
// tanh(m+d) = 1 - 2/(Em*Ed+1)  with Em=exp(2m), Ed=exp(2d) precomputed.
// ---------------------------------------------------------------------------
__global__ __launch_bounds__(256) void attn_conv(const float* __restrict__ Em,
                                                 const float* __restrict__ Ed,
                                                 const float* __restrict__ vw,
                                                 float* __restrict__ scores,
                                                 const float* __restrict__ Wo2,
                                                 unsigned short* __restrict__ Wo2_bf) {
    const int bid = blockIdx.x;
    const int tid = threadIdx.x;
    if (bid >= 1024) {
        int i = (bid - 1024) * 256 + tid;   // uint4 index, 1605632 total
        if (i < 1600000)
            reinterpret_cast<uint4*>(Wo2_bf)[i] = cvt8(Wo2 + (size_t)i * 8);
        else
            reinterpret_cast<uint4*>(Wo2_bf)[i] = make_uint4(0u, 0u, 0u, 0u);
        return;
    }
    __shared__ float ms[16][132];
    __shared__ float dsh[16][132];
    __shared__ float vs[128];
    const int t0 = (bid & 31) * 16, b0 = (bid >> 5) * 16;
    const int tl = tid & 15, bl = tid >> 4;
    float acc2 = 0.f, sv = 0.f;
    for (int d0 = 0; d0 < 512; d0 += 128) {
#pragma unroll
        for (int u = 0; u < 2; ++u) {
            int fi = tid + u * 256;
            int r = fi >> 5, c4 = fi & 31;
            *reinterpret_cast<float4*>(&ms[r][c4 * 4]) =
                *reinterpret_cast<const float4*>(&Em[(size_t)(t0 + r) * 512 + d0 + c4 * 4]);
            *reinterpret_cast<float4*>(&dsh[r][c4 * 4]) =
                *reinterpret_cast<const float4*>(&Ed[(size_t)(b0 + r) * 512 + d0 + c4 * 4]);
        }
        if (tid < 32)
            *reinterpret_cast<float4*>(&vs[tid * 4]) =
                *reinterpret_cast<const float4*>(&vw[d0 + tid * 4]);
        __syncthreads();
#pragma unroll 8
        for (int j = 0; j < 128; j += 4) {
            float4 mv = *reinterpret_cast<const float4*>(&ms[tl][j]);
            float4 dv = *reinterpret_cast<const float4*>(&dsh[bl][j]);
            float4 wv = *reinterpret_cast<const float4*>(&vs[j]);
            acc2 += wv.x * fast_rcp(__builtin_fmaf(mv.x, dv.x, 1.f));
            acc2 += wv.y * fast_rcp(__builtin_fmaf(mv.y, dv.y, 1.f));
            acc2 += wv.z * fast_rcp(__builtin_fmaf(mv.z, dv.z, 1.f));
            acc2 += wv.w * fast_rcp(__builtin_fmaf(mv.w, dv.w, 1.f));
            sv += wv.x + wv.y + wv.z + wv.w;
        }
        __syncthreads();
    }
    scores[(size_t)(b0 + bl) * 512 + (t0 + tl)] = sv - 2.f * acc2;
}

// ---------------------------------------------------------------------------
// Fused softmax + c_t. 64 blocks x 512 threads.
// ---------------------------------------------------------------------------
__global__ __launch_bounds__(512) void softmax_ct(const float* __restrict__ scores,
                                                  const float* __restrict__ mem,
                                                  float* __restrict__ attn_out,
                                                  float* __restrict__ ct_out,
                                                  unsigned short* __restrict__ hc_bf) {
    __shared__ float sl[8][512];
    const int tid = threadIdx.x;
    const int b0 = blockIdx.x * 8;
#pragma unroll
    for (int i = 0; i < 8; ++i) {
        int idx = tid + i * 512;
        int r = idx >> 9, c = idx & 511;
        sl[r][c] = scores[(size_t)(b0 + r) * 512 + c];
    }
    __syncthreads();
    {
        int r = tid >> 6, li = tid & 63;
        float mx = -1e30f;
#pragma unroll
        for (int k = 0; k < 8; ++k) mx = fmaxf(mx, sl[r][li + k * 64]);
#pragma unroll
        for (int m = 1; m < 64; m <<= 1) mx = fmaxf(mx, __shfl_xor(mx, m));
        float pv[8];
        float sum = 0.f;
#pragma unroll
        for (int k = 0; k < 8; ++k) {
            float p = __expf(sl[r][li + k * 64] - mx);
            pv[k] = p;
            sum += p;
        }
#pragma unroll
        for (int m = 1; m < 64; m <<= 1) sum += __shfl_xor(sum, m);
        float inv = 1.f / sum;
#pragma unroll
        for (int k = 0; k < 8; ++k) {
            float a = pv[k] * inv;
            sl[r][li + k * 64] = a;
            attn_out[(size_t)(b0 + r) * 512 + li + k * 64] = a;
        }
    }
    __syncthreads();
    const int d = tid;
    float acc[8] = {};
    for (int t = 0; t < 512; t += 2) {
        float m0v = mem[(size_t)t * 512 + d];
        float m1v = mem[(size_t)(t + 1) * 512 + d];
#pragma unroll
        for (int r = 0; r < 8; ++r) {
            acc[r] += sl[r][t] * m0v;
            acc[r] += sl[r][t + 1] * m1v;
        }
    }
#pragma unroll
    for (int r = 0; r < 8; ++r) {
        int b = b0 + r;
        ct_out[(size_t)b * 512 + d] = acc[r];
        hc_bf[(size_t)b * 768 + 256 + d] = (unsigned short)f2bf1(acc[r]);
    }
}

// ---------------------------------------------------------------------------
// Finish: fused {rowsum over ps (coalesced, transposed layout) + p_gen dot}
// -> scale bf16 exp-stash into f32 row + extra_zeros, coverage copy,
// scatter-add. 512 blocks x 1024 thr.
// ---------------------------------------------------------------------------
__global__ __launch_bounds__(1024) void finish_k(float* __restrict__ outF,
                                                 const float* __restrict__ ps,
                                                 const float* __restrict__ ct,
                                                 const float* __restrict__ scat,
                                                 const float* __restrict__ xw,
                                                 const float* __restrict__ Wpg,
                                                 const float* __restrict__ bpg,
                                                 float* __restrict__ outPG,
                                                 const float* __restrict__ ez,
                                                 const float* __restrict__ attn,
                                                 const int* __restrict__ ebev,
                                                 const float* __restrict__ cov,
                                                 float* __restrict__ outCov) {
    const int b = blockIdx.x;
    const int tid = threadIdx.x;
    __shared__ float sred[16], pgred[16], shsc[2];

    // --- fused rowsum + p_gen (ps row is contiguous: coalesced read) ---
    float sp = 0.f;
    if (tid < 2 * NCB_)
        sp = ps[(size_t)b * (2 * NCB_) + tid];
    float pgp = 0.f;
    for (int idx = tid; idx < 1280; idx += 1024) {
        float wv = Wpg[idx];
        float xv;
        if (idx < 512) xv = ct[(size_t)b * 512 + idx];
        else if (idx < 1024) xv = scat[(size_t)b * 512 + idx - 512];
        else xv = xw[(size_t)b * 256 + idx - 1024];
        pgp += wv * xv;
    }
#pragma unroll
    for (int m = 1; m < 64; m <<= 1) {
        sp += __shfl_xor(sp, m);
        pgp += __shfl_xor(pgp, m);
    }
    if ((tid & 63) == 0) { sred[tid >> 6] = sp; pgred[tid >> 6] = pgp; }
    __syncthreads();
    if (tid == 0) {
        float s = 0.f, pg = 0.f;
#pragma unroll
        for (int i = 0; i < 16; ++i) { s += sred[i]; pg += pgred[i]; }
        float pgv = fast_sig(pg + bpg[0]);
        outPG[b] = pgv;
        shsc[0] = pgv / s;
        shsc[1] = 1.f - pgv;
    }
    __syncthreads();
    const float s = shsc[0];
    const float ad = shsc[1];

    // --- scale stash -> f32 row (in-place safe: read all, barrier, write) ---
    float* row = outF + (size_t)b * VE_;
    const unsigned short* el = (const unsigned short*)(row + ELOFF);
    uint2 buf[13];
    float4 ezbuf;
#pragma unroll
    for (int k = 0; k < 13; ++k) {
        int c4 = tid + (k << 10);
        if (c4 < 12500)
            buf[k] = *reinterpret_cast<const uint2*>(el + c4 * 4);
        else if (c4 < 12516)
            ezbuf = *reinterpret_cast<const float4*>(&ez[(size_t)b * NOOV_ + (c4 - 12500) * 4]);
    }
    __syncthreads();
#pragma unroll
    for (int k = 0; k < 13; ++k) {
        int c4 = tid + (k << 10);
        if (c4 < 12500) {
            uint2 e = buf[k];
            float4 v;
            v.x = __uint_as_float((e.x & 0xffffu) << 16) * s;
            v.y = __uint_as_float(e.x & 0xffff0000u) * s;
            v.z = __uint_as_float((e.y & 0xffffu) << 16) * s;
            v.w = __uint_as_float(e.y & 0xffff0000u) * s;
            *reinterpret_cast<float4*>(row + c4 * 4) = v;
        } else if (c4 < 12516) {
            *reinterpret_cast<float4*>(row + c4 * 4) = ezbuf;
        }
    }
    if (tid < 128)
        reinterpret_cast<float4*>(outCov + (size_t)b * 512)[tid] =
            reinterpret_cast<const float4*>(cov + (size_t)b * 512)[tid];
    __syncthreads();
    if (tid < 512) {
        int col = ebev[(size_t)b * 512 + tid];
        float val = ad * attn[(size_t)b * 512 + tid];
        atomicAdd(&row[col], val);
    }
}

// ---------------------------------------------------------------------------
extern "C" void kernel_launch(void* const* d_in, const int* in_sizes, int n_in,
                              void* d_out, int out_size, void* d_ws, size_t ws_size,
                              hipStream_t stream) {
    const int*   y    = (const int*)d_in[0];
    const float* h0   = (const float*)d_in[1];
    const float* c0   = (const float*)d_in[2];
    const float* ct1  = (const float*)d_in[3];
    const float* ez   = (const float*)d_in[4];
    const int*   ebev = (const int*)d_in[5];
    const float* cov  = (const float*)d_in[6];
    const float* emb  = (const float*)d_in[7];
    const float* Wx   = (const float*)d_in[8];
    const float* bx   = (const float*)d_in[9];
    const float* Wih  = (const float*)d_in[10];
    const float* Whh  = (const float*)d_in[11];
    const float* bih  = (const float*)d_in[12];
    const float* bhh  = (const float*)d_in[13];
    const float* memp = (const float*)d_in[14];
    const float* Wdp  = (const float*)d_in[15];
    const float* bdp  = (const float*)d_in[16];
    const float* vw   = (const float*)d_in[17];
    const float* Wpg  = (const float*)d_in[18];
    const float* bpg  = (const float*)d_in[19];
    const float* Wo1  = (const float*)d_in[20];
    const float* bo1  = (const float*)d_in[21];
    const float* Wo2  = (const float*)d_in[22];
    const float* bo2  = (const float*)d_in[23];

    float* out = (float*)d_out;
    const size_t OUT_FINAL = 0;
    const size_t OUT_H    = (size_t)B_ * VE_;
    const size_t OUT_C    = OUT_H + (size_t)B_ * H_;
    const size_t OUT_CT   = OUT_C + (size_t)B_ * H_;
    const size_t OUT_ATTN = OUT_CT + (size_t)B_ * 2 * H_;
    const size_t OUT_PG   = OUT_ATTN + (size_t)B_ * TK_;
    const size_t OUT_COV  = OUT_PG + B_;

    // ---- workspace layout ----
    char* wb = (char*)d_ws;
    float* xw     = (float*)wb;                       // 131072
    float* scat   = xw + 131072;                      // 262144
    float* Ed     = scat + 262144;                    // 262144
    float* scores = Ed + 262144;                      // 262144
    float* ps     = scores + 262144;                  // 400384
    float* Em     = ps + 400384;                      // 262144
    float* bsum   = Em + 262144;                      // 1024
    unsigned short* Wx_bf   = (unsigned short*)(bsum + 1024);
    unsigned short* Wcat_bf = Wx_bf + 196608;
    unsigned short* Wdp_bf  = Wcat_bf + 524288;
    unsigned short* Wo1_bf  = Wdp_bf + 262144;
    unsigned short* xcat_bf = Wo1_bf + 196608;
    unsigned short* xh_bf   = xcat_bf + 393216;
    unsigned short* scat_bf = xh_bf + 262144;
    unsigned short* hc_bf   = scat_bf + 262144;
    unsigned short* out1_bf = hc_bf + 393216;
    unsigned short* Wo2_bf  = out1_bf + 131072;       // 50176*256 ushorts

    // 0) small conversions / gathers (Wcat gate-interleaved, Em=exp(2*mem))
    prep_small<<<(PR_END + 255) / 256, 256, 0, stream>>>(
        Wx, Wdp, Wo1, Wih, Whh, bih, bhh, y, ct1, emb, h0, memp,
        Wx_bf, Wdp_bf, Wo1_bf, Wcat_bf, xcat_bf, xh_bf, Em, bsum);

    // 1) x = cat(c_t_1, emb[y]) @ Wx^T + bx  -> f32 xw + bf16 into xh_bf[:,0:256]
    gemm64<<<dim3(4, 8), 256, 0, stream>>>(xcat_bf, Wx_bf, bx, xw, xh_bf,
                                           256, 768, 512, 0, 0);

    // 2) LSTM gates GEMM + fused pointwise
    gemm_lstm<<<dim3(16, 8), 256, 0, stream>>>(xh_bf, Wcat_bf, bsum, c0,
                                               out + OUT_H, out + OUT_C,
                                               scat, scat_bf, hc_bf);

    // 3) attention: Ed = exp(2*(s_t_hat @ Wdp^T + bdp)) via mode=2 epilogue
    gemm64<<<dim3(8, 8), 256, 0, stream>>>(scat_bf, Wdp_bf, bdp, Ed, nullptr,
                                           512, 512, 0, 0, 2);
    attn_conv<<<7296, 256, 0, stream>>>(Em, Ed, vw, scores, Wo2, Wo2_bf);
    softmax_ct<<<64, 512, 0, stream>>>(scores, memp, out + OUT_ATTN,
                                       out + OUT_CT, hc_bf);

    // 4) vocab distribution: out1 -> exp-stash + partial sums
    gemm64<<<dim3(4, 8), 256, 0, stream>>>(hc_bf, Wo1_bf, bo1, nullptr, out1_bf,
                                           256, 768, 256, 0, 1);
    gemm_sum<<<1564, 1024, 0, stream>>>(out1_bf, Wo2_bf, bo2, out + OUT_FINAL, ps);

    // 5) finish: rowsum + p_gen + scale + extra_zeros + coverage + scatter
    finish_k<<<512, 1024, 0, stream>>>(out + OUT_FINAL, ps, out + OUT_CT, scat,
                                       xw, Wpg, bpg, out + OUT_PG, ez,
                                       out + OUT_ATTN, ebev, cov, out + OUT_COV);
}

// Round 13
// 185.599 us; speedup vs baseline: 1.1176x; 1.0197x over previous
//
#include <hip/hip_runtime.h>
#include <hip/hip_bf16.h>

// Problem constants
#define B_  512
#define H_  256
#define TK_ 512
#define V_  50000
#define NOOV_ 64
#define VE_ (V_ + NOOV_)   // 50064
#define NCB_ 391           // ceil(50000/128)
#define VPAD_ 50176        // 392*128, padded Wo2_bf rows
#define ELOFF 25032        // float offset of bf16 exp-stash inside each out row

typedef __bf16 bf16_t;
typedef __bf16 bf16x8 __attribute__((ext_vector_type(8)));
typedef float  f32x4  __attribute__((ext_vector_type(4)));

#define DEVI __device__ __forceinline__

DEVI float fast_rcp(float x) { return __builtin_amdgcn_rcpf(x); }
DEVI float fast_tanh(float x) {
    float e = __expf(2.f * x);
    return 1.f - 2.f * fast_rcp(e + 1.f);
}
DEVI float fast_sig(float x) { return fast_rcp(1.f + __expf(-x)); }

DEVI unsigned f2bf1(float f) {
    unsigned u = __float_as_uint(f);
    return (u + 0x7fffu + ((u >> 16) & 1u)) >> 16;   // RNE
}

DEVI uint4 cvt8(const float* p) {
    float4 a = *reinterpret_cast<const float4*>(p);
    float4 b = *reinterpret_cast<const float4*>(p + 4);
    bf16x8 v;
    v[0] = (__bf16)a.x; v[1] = (__bf16)a.y; v[2] = (__bf16)a.z; v[3] = (__bf16)a.w;
    v[4] = (__bf16)b.x; v[5] = (__bf16)b.y; v[6] = (__bf16)b.z; v[7] = (__bf16)b.w;
    return *reinterpret_cast<uint4*>(&v);
}

DEVI void gload_lds16(const void* g, void* l) {
    __builtin_amdgcn_global_load_lds(
        (const __attribute__((address_space(1))) void*)g,
        (__attribute__((address_space(3))) void*)l, 16, 0, 0);
}

// ---------------------------------------------------------------------------
// All small conversions / gathers in one kernel (uint4-granular items)
// Wcat gate-interleaved; also precomputes Em = exp(2*mem) for attn.
// ---------------------------------------------------------------------------
#define PR_O1 24576    // Wx end
#define PR_O2 57344    // Wdp end
#define PR_O3 81920    // Wo1 end
#define PR_O4 147456   // Wcat end
#define PR_O5 196608   // xcat end
#define PR_O6 212992   // xh-h0 end
#define PR_EM 245760   // Em end (32768 items of 8 floats)
#define PR_END 245888  // bsum end

__global__ __launch_bounds__(256) void prep_small(
        const float* __restrict__ Wx, const float* __restrict__ Wdp,
        const float* __restrict__ Wo1,
        const float* __restrict__ Wih, const float* __restrict__ Whh,
        const float* __restrict__ bih, const float* __restrict__ bhh,
        const int* __restrict__ y, const float* __restrict__ ct1,
        const float* __restrict__ emb, const float* __restrict__ h0,
        const float* __restrict__ mem,
        unsigned short* __restrict__ Wx_bf, unsigned short* __restrict__ Wdp_bf,
        unsigned short* __restrict__ Wo1_bf, unsigned short* __restrict__ Wcat_bf,
        unsigned short* __restrict__ xcat_bf, unsigned short* __restrict__ xh_bf,
        float* __restrict__ Em, float* __restrict__ bsum) {
    int idx = blockIdx.x * 256 + threadIdx.x;
    if (idx >= PR_END) return;
    if (idx < PR_O1) {
        reinterpret_cast<uint4*>(Wx_bf)[idx] = cvt8(Wx + (size_t)idx * 8);
    } else if (idx < PR_O2) {
        int i = idx - PR_O1;
        reinterpret_cast<uint4*>(Wdp_bf)[i] = cvt8(Wdp + (size_t)i * 8);
    } else if (idx < PR_O3) {
        int i = idx - PR_O2;
        reinterpret_cast<uint4*>(Wo1_bf)[i] = cvt8(Wo1 + (size_t)i * 8);
    } else if (idx < PR_O4) {
        int i = idx - PR_O3;
        int rp = i >> 6, c = (i & 63) * 8;
        int g = rp & 3, j = rp >> 2;
        const float* src = (c < 256) ? &Wih[(size_t)(g * 256 + j) * 256 + c]
                                     : &Whh[(size_t)(g * 256 + j) * 256 + (c - 256)];
        *reinterpret_cast<uint4*>(&Wcat_bf[(size_t)rp * 512 + c]) = cvt8(src);
    } else if (idx < PR_O5) {
        int i = idx - PR_O4;
        int b = i / 96, j = (i - b * 96) * 8;
        const float* src = (j < 512) ? &ct1[(size_t)b * 512 + j]
                                     : &emb[(size_t)y[b] * 256 + (j - 512)];
        *reinterpret_cast<uint4*>(&xcat_bf[(size_t)b * 768 + j]) = cvt8(src);
    } else if (idx < PR_O6) {
        int i = idx - PR_O5;
        int b = i >> 5, c = (i & 31) * 8;
        *reinterpret_cast<uint4*>(&xh_bf[(size_t)b * 512 + 256 + c]) =
            cvt8(&h0[(size_t)b * 256 + c]);
    } else if (idx < PR_EM) {
        int i = idx - PR_O6;
        const float* src = mem + (size_t)i * 8;
        float4 a = *reinterpret_cast<const float4*>(src);
        float4 b = *reinterpret_cast<const float4*>(src + 4);
        float4 ea, eb;
        ea.x = __expf(2.f * a.x); ea.y = __expf(2.f * a.y);
        ea.z = __expf(2.f * a.z); ea.w = __expf(2.f * a.w);
        eb.x = __expf(2.f * b.x); eb.y = __expf(2.f * b.y);
        eb.z = __expf(2.f * b.z); eb.w = __expf(2.f * b.w);
        *reinterpret_cast<float4*>(Em + (size_t)i * 8) = ea;
        *reinterpret_cast<float4*>(Em + (size_t)i * 8 + 4) = eb;
    } else {
        int g0 = (idx - PR_EM) * 8;
#pragma unroll
        for (int k = 0; k < 8; ++k) {
            int rp = g0 + k;
            int g = rp & 3, j = rp >> 2;
            bsum[rp] = bih[g * 256 + j] + bhh[g * 256 + j];
        }
    }
}

// ---------------------------------------------------------------------------
// Small GEMM: C[M,N] = A[M,K](bf16) * B[N,K]^T(bf16) + bias
// BM=BN=64, BK=64, 256 threads. mode: 0 none, 1 relu, 2 exp(2x) (Cf only).
// ---------------------------------------------------------------------------
__global__ __launch_bounds__(256) void gemm64(const unsigned short* __restrict__ Abf,
                                              const unsigned short* __restrict__ Bbf,
                                              const float* __restrict__ bias,
                                              float* __restrict__ Cf,
                                              unsigned short* __restrict__ Cb,
                                              int N, int K, int ldcb, int ocb,
                                              int mode) {
    __shared__ unsigned short As[2][4096];
    __shared__ unsigned short Bs[2][4096];
    const int tid = threadIdx.x;
    const int m0 = blockIdx.y * 64;
    const int n0 = blockIdx.x * 64;
    const int lane = tid & 63;
    const int wid = tid >> 6;
    const int wm = wid >> 1, wn = wid & 1;
    const int r16 = lane & 15, kq = lane >> 4;
    const int lrow = lane >> 3;               // 0..7
    const int lcol = (lane & 7) ^ lrow;       // swizzled source 16B-chunk
    const int ch0 = wid * 2;                  // 2 chunks/wave/matrix (8 total)

    f32x4 acc[2][2] = {};
    const int nt = K >> 6;

#define G64_STAGE(p, k0)                                                       \
    {                                                                          \
        _Pragma("unroll")                                                      \
        for (int i = 0; i < 2; ++i) {                                          \
            int ch = ch0 + i;                                                  \
            int row = ch * 8 + lrow;                                           \
            gload_lds16(&Abf[(size_t)(m0 + row) * K + (k0) + lcol * 8],        \
                        &As[p][ch * 512]);                                     \
            gload_lds16(&Bbf[(size_t)(n0 + row) * K + (k0) + lcol * 8],        \
                        &Bs[p][ch * 512]);                                     \
        }                                                                      \
    }

    G64_STAGE(0, 0);
    __syncthreads();
    int cur = 0;
    for (int t = 0; t < nt; ++t) {
        if (t + 1 < nt) G64_STAGE(cur ^ 1, (t + 1) << 6);
#pragma unroll
        for (int ks = 0; ks < 64; ks += 32) {
            int cbase = (ks >> 3) + kq;
            bf16x8 af[2], bfv[2];
#pragma unroll
            for (int mi = 0; mi < 2; ++mi) {
                int row = wm * 32 + mi * 16 + r16;
                af[mi] = *reinterpret_cast<const bf16x8*>(
                    &As[cur][row * 64 + (cbase ^ (row & 7)) * 8]);
            }
#pragma unroll
            for (int ni = 0; ni < 2; ++ni) {
                int row = wn * 32 + ni * 16 + r16;
                bfv[ni] = *reinterpret_cast<const bf16x8*>(
                    &Bs[cur][row * 64 + (cbase ^ (row & 7)) * 8]);
            }
#pragma unroll
            for (int mi = 0; mi < 2; ++mi)
#pragma unroll
                for (int ni = 0; ni < 2; ++ni)
                    acc[mi][ni] = __builtin_amdgcn_mfma_f32_16x16x32_bf16(af[mi], bfv[ni], acc[mi][ni], 0, 0, 0);
        }
        __syncthreads();
        cur ^= 1;
    }

#pragma unroll
    for (int mi = 0; mi < 2; ++mi)
#pragma unroll
        for (int ni = 0; ni < 2; ++ni) {
            int c = n0 + wn * 32 + ni * 16 + r16;
            float bv = bias[c];
#pragma unroll
            for (int r = 0; r < 4; ++r) {
                int rr = m0 + wm * 32 + mi * 16 + kq * 4 + r;
                float v = acc[mi][ni][r] + bv;
                if (mode == 1) v = fmaxf(v, 0.f);
                if (mode == 2) v = __expf(2.f * v);
                if (Cf) Cf[(size_t)rr * N + c] = v;
                if (Cb) Cb[(size_t)rr * ldcb + ocb + c] = (unsigned short)f2bf1(v);
            }
        }
}

// ---------------------------------------------------------------------------
// Gates GEMM + fused LSTM pointwise. (round-8 proven structure)
// ---------------------------------------------------------------------------
__global__ __launch_bounds__(256) void gemm_lstm(const unsigned short* __restrict__ Abf,
                                                 const unsigned short* __restrict__ Bbf,
                                                 const float* __restrict__ bsum,
                                                 const float* __restrict__ c0,
                                                 float* __restrict__ outH,
                                                 float* __restrict__ outC,
                                                 float* __restrict__ scat,
                                                 unsigned short* __restrict__ scat_bf,
                                                 unsigned short* __restrict__ hc_bf) {
    __shared__ unsigned short As[2][4096];
    __shared__ unsigned short Bs[2][4096];
    __shared__ float gsh[64][68];
    const int tid = threadIdx.x;
    const int m0 = blockIdx.y * 64;
    const int n0 = blockIdx.x * 64;
    const int lane = tid & 63;
    const int wid = tid >> 6;
    const int wm = wid >> 1, wn = wid & 1;
    const int r16 = lane & 15, kq = lane >> 4;
    const int lrow = lane >> 3;
    const int lcol = (lane & 7) ^ lrow;
    const int ch0 = wid * 2;

    f32x4 acc[2][2] = {};

#define GL_STAGE(p, k0)                                                        \
    {                                                                          \
        _Pragma("unroll")                                                      \
        for (int i = 0; i < 2; ++i) {                                          \
            int ch = ch0 + i;                                                  \
            int row = ch * 8 + lrow;                                           \
            gload_lds16(&Abf[(size_t)(m0 + row) * 512 + (k0) + lcol * 8],      \
                        &As[p][ch * 512]);                                     \
            gload_lds16(&Bbf[(size_t)(n0 + row) * 512 + (k0) + lcol * 8],      \
                        &Bs[p][ch * 512]);                                     \
        }                                                                      \
    }

    GL_STAGE(0, 0);
    __syncthreads();
    int cur = 0;
#pragma unroll
    for (int t = 0; t < 8; ++t) {
        if (t < 7) GL_STAGE(cur ^ 1, (t + 1) << 6);
#pragma unroll
        for (int ks = 0; ks < 64; ks += 32) {
            int cbase = (ks >> 3) + kq;
            bf16x8 af[2], bfv[2];
#pragma unroll
            for (int mi = 0; mi < 2; ++mi) {
                int row = wm * 32 + mi * 16 + r16;
                af[mi] = *reinterpret_cast<const bf16x8*>(
                    &As[cur][row * 64 + (cbase ^ (row & 7)) * 8]);
            }
#pragma unroll
            for (int ni = 0; ni < 2; ++ni) {
                int row = wn * 32 + ni * 16 + r16;
                bfv[ni] = *reinterpret_cast<const bf16x8*>(
                    &Bs[cur][row * 64 + (cbase ^ (row & 7)) * 8]);
            }
#pragma unroll
            for (int mi = 0; mi < 2; ++mi)
#pragma unroll
                for (int ni = 0; ni < 2; ++ni)
                    acc[mi][ni] = __builtin_amdgcn_mfma_f32_16x16x32_bf16(af[mi], bfv[ni], acc[mi][ni], 0, 0, 0);
        }
        __syncthreads();
        cur ^= 1;
    }

#pragma unroll
    for (int mi = 0; mi < 2; ++mi)
#pragma unroll
        for (int ni = 0; ni < 2; ++ni) {
            int cl = wn * 32 + ni * 16 + r16;
            float bv = bsum[n0 + cl];
#pragma unroll
            for (int r = 0; r < 4; ++r) {
                int rl = wm * 32 + mi * 16 + kq * 4 + r;
                gsh[rl][cl] = acc[mi][ni][r] + bv;
            }
        }
    __syncthreads();
    const int j0 = n0 >> 2;
#pragma unroll
    for (int u = tid; u < 1024; u += 256) {
        int bl = u >> 4, jl = u & 15;
        float4 g4 = *reinterpret_cast<const float4*>(&gsh[bl][jl * 4]);
        int b = m0 + bl, j = j0 + jl;
        float ig = fast_sig(g4.x);
        float fg = fast_sig(g4.y);
        float gg = fast_tanh(g4.z);
        float og = fast_sig(g4.w);
        float c = fg * c0[(size_t)b * 256 + j] + ig * gg;
        float h = og * fast_tanh(c);
        outH[(size_t)b * 256 + j] = h;
        outC[(size_t)b * 256 + j] = c;
        scat[(size_t)b * 512 + j] = h;
        scat[(size_t)b * 512 + 256 + j] = c;
        unsigned short hb = (unsigned short)f2bf1(h);
        unsigned short cbf = (unsigned short)f2bf1(c);
        scat_bf[(size_t)b * 512 + j] = hb;
        scat_bf[(size_t)b * 512 + 256 + j] = cbf;
        hc_bf[(size_t)b * 768 + j] = hb;
    }
}

// ---------------------------------------------------------------------------
// Vocab GEMM (round-8 proven K-loop; epilogue now stages the 128x128 bf16
// exp-tile in LDS (reusing As) and writes 2048 coalesced uint4 stores
// instead of 16384 scattered 2B stores). 1024 thr = 16 waves (8 wm x 2 wn).
// ps TRANSPOSED: ps[rr*782 + cb*2 + wn] so finish_k reads coalesced.
// 1D grid 1564, XCD-swizzled so the 4 m-blocks of a cb share an XCD L2.
// ---------------------------------------------------------------------------
__global__ __launch_bounds__(1024, 8) void gemm_sum(const unsigned short* __restrict__ Abf,
                                                    const unsigned short* __restrict__ Bbf,
                                                    const float* __restrict__ bo2,
                                                    float* __restrict__ outF,
                                                    float* __restrict__ ps) {
    __shared__ unsigned short As[2][8192];
    __shared__ unsigned short Bs[2][8192];
    const int f = blockIdx.x;
    int cb, mB;
    if (f < 1536) { cb = (f >> 5) * 8 + (f & 7); mB = (f >> 3) & 3; }
    else { int t = f - 1536; cb = 384 + t % 7; mB = t / 7; }
    const int tid = threadIdx.x;
    const int m0 = mB * 128;
    const int n0 = cb * 128;
    const int lane = tid & 63;
    const int wid = tid >> 6;                 // 0..15
    const int wm = wid >> 1, wn = wid & 1;    // 8 x 2
    const int r16 = lane & 15, kq = lane >> 4;
    const int lrow = lane >> 3;
    const int lcol = (lane & 7) ^ lrow;

#define GS_STAGE(p, k0)                                                        \
    {                                                                          \
        int row = wid * 8 + lrow;                                              \
        gload_lds16(&Abf[(size_t)(m0 + row) * 256 + (k0) + lcol * 8],          \
                    &As[p][wid * 512]);                                        \
        gload_lds16(&Bbf[(size_t)(n0 + row) * 256 + (k0) + lcol * 8],          \
                    &Bs[p][wid * 512]);                                        \
    }

    GS_STAGE(0, 0);
    __syncthreads();
    f32x4 acc[4] = {};
    int cur = 0;
#pragma unroll
    for (int t = 0; t < 4; ++t) {
        if (t < 3) GS_STAGE(cur ^ 1, (t + 1) * 64);
#pragma unroll
        for (int ks = 0; ks < 64; ks += 32) {
            const int cbase = (ks >> 3) + kq;
            const int arow = wm * 16 + r16;
            bf16x8 af = *reinterpret_cast<const bf16x8*>(
                &As[cur][arow * 64 + (cbase ^ (arow & 7)) * 8]);
#pragma unroll
            for (int ni = 0; ni < 4; ++ni) {
                int brow = wn * 64 + ni * 16 + r16;
                bf16x8 bv = *reinterpret_cast<const bf16x8*>(
                    &Bs[cur][brow * 64 + (cbase ^ (brow & 7)) * 8]);
                acc[ni] = __builtin_amdgcn_mfma_f32_16x16x32_bf16(af, bv, acc[ni], 0, 0, 0);
            }
        }
        __syncthreads();
        cur ^= 1;
    }

    // --- epilogue: exp -> bf16 into LDS tile (reuse As, dead after loop) ---
    unsigned short* tile = &As[0][0];        // 128 x 128 ushorts = 32 KB
    float psum[4] = {0.f, 0.f, 0.f, 0.f};
#pragma unroll
    for (int ni = 0; ni < 4; ++ni) {
        int cl = wn * 64 + ni * 16 + r16;
        int c = n0 + cl;
        bool ok = (c < V_);
        float bv = ok ? bo2[c] : 0.f;
#pragma unroll
        for (int r = 0; r < 4; ++r) {
            int rl = wm * 16 + kq * 4 + r;
            float p = __expf(acc[ni][r] + bv);
            unsigned eb = f2bf1(p);
            tile[rl * 128 + cl] = (unsigned short)eb;
            if (ok) psum[r] += __uint_as_float(eb << 16);
        }
    }

#pragma unroll
    for (int r = 0; r < 4; ++r) {
        float v = psum[r];
        v += __shfl_xor(v, 1);
        v += __shfl_xor(v, 2);
        v += __shfl_xor(v, 4);
        v += __shfl_xor(v, 8);
        if (r16 == 0) {
            int rr = m0 + wm * 16 + kq * 4 + r;
            ps[(size_t)rr * (2 * NCB_) + cb * 2 + wn] = v;
        }
    }
    __syncthreads();

    // --- coalesced stash write: 2048 uint4 chunks (8 cols each) ---
#pragma unroll
    for (int i = tid; i < 2048; i += 1024) {
        int rl = i >> 4;                      // 0..127
        int cc = i & 15;                      // 16B chunk within the 128 cols
        int c = n0 + cc * 8;
        if (c < V_) {                         // V_ % 8 == 0 -> whole chunk valid
            unsigned short* el =
                (unsigned short*)(outF + (size_t)(m0 + rl) * VE_ + ELOFF);
            *reinterpret_cast<uint4*>(el + c) =
                *reinterpret_cast<const uint4*>(tile + rl * 128 + cc * 8);
        }
    }
}

// ---------------------------------------------------------------------------
// Fused: attention scores (blocks 0..1023) + Wo2 f32->bf16 conversion
// (blocks 1024..7295). scores via factored tanh:
// tanh(m+d) = 1 - 2/(Em*Ed+1)  with Em=exp(2m), Ed=exp(2d) precomputed.
// ---------------------------------------------------------------------------
__global__ __launch_bounds__(256) void attn_conv(const float* __restrict__ Em,
                                                 const float* __restrict__ Ed,
                                                 const float* __restrict__ vw,
                                                 float* __restrict__ scores,
                                                 const float* __restrict__ Wo2,
                                                 unsigned short* __restrict__ Wo2_bf) {
    const int bid = blockIdx.x;
    const int tid = threadIdx.x;
    if (bid >= 1024) {
        int i = (bid - 1024) * 256 + tid;   // uint4 index, 1605632 total
        if (i < 1600000)
            reinterpret_cast<uint4*>(Wo2_bf)[i] = cvt8(Wo2 + (size_t)i * 8);
        else
            reinterpret_cast<uint4*>(Wo2_bf)[i] = make_uint4(0u, 0u, 0u, 0u);
        return;
    }
    __shared__ float ms[16][132];
    __shared__ float dsh[16][132];
    __shared__ float vs[128];
    const int t0 = (bid & 31) * 16, b0 = (bid >> 5) * 16;
    const int tl = tid & 15, bl = tid >> 4;
    float acc2 = 0.f, sv = 0.f;
    for (int d0 = 0; d0 < 512; d0 += 128) {
#pragma unroll
        for (int u = 0; u < 2; ++u) {
            int fi = tid + u * 256;
            int r = fi >> 5, c4 = fi & 31;
            *reinterpret_cast<float4*>(&ms[r][c4 * 4]) =
                *reinterpret_cast<const float4*>(&Em[(size_t)(t0 + r) * 512 + d0 + c4 * 4]);
            *reinterpret_cast<float4*>(&dsh[r][c4 * 4]) =
                *reinterpret_cast<const float4*>(&Ed[(size_t)(b0 + r) * 512 + d0 + c4 * 4]);
        }
        if (tid < 32)
            *reinterpret_cast<float4*>(&vs[tid * 4]) =
                *reinterpret_cast<const float4*>(&vw[d0 + tid * 4]);
        __syncthreads();
#pragma unroll 8
        for (int j = 0; j < 128; j += 4) {
            float4 mv = *reinterpret_cast<const float4*>(&ms[tl][j]);
            float4 dv = *reinterpret_cast<const float4*>(&dsh[bl][j]);
            float4 wv = *reinterpret_cast<const float4*>(&vs[j]);
            acc2 += wv.x * fast_rcp(__builtin_fmaf(mv.x, dv.x, 1.f));
            acc2 += wv.y * fast_rcp(__builtin_fmaf(mv.y, dv.y, 1.f));
            acc2 += wv.z * fast_rcp(__builtin_fmaf(mv.z, dv.z, 1.f));
            acc2 += wv.w * fast_rcp(__builtin_fmaf(mv.w, dv.w, 1.f));
            sv += wv.x + wv.y + wv.z + wv.w;
        }
        __syncthreads();
    }
    scores[(size_t)(b0 + bl) * 512 + (t0 + tl)] = sv - 2.f * acc2;
}

// ---------------------------------------------------------------------------
// Fused softmax + c_t. 64 blocks x 512 threads.
// ---------------------------------------------------------------------------
__global__ __launch_bounds__(512) void softmax_ct(const float* __restrict__ scores,
                                                  const float* __restrict__ mem,
                                                  float* __restrict__ attn_out,
                                                  float* __restrict__ ct_out,
                                                  unsigned short* __restrict__ hc_bf) {
    __shared__ float sl[8][512];
    const int tid = threadIdx.x;
    const int b0 = blockIdx.x * 8;
#pragma unroll
    for (int i = 0; i < 8; ++i) {
        int idx = tid + i * 512;
        int r = idx >> 9, c = idx & 511;
        sl[r][c] = scores[(size_t)(b0 + r) * 512 + c];
    }
    __syncthreads();
    {
        int r = tid >> 6, li = tid & 63;
        float mx = -1e30f;
#pragma unroll
        for (int k = 0; k < 8; ++k) mx = fmaxf(mx, sl[r][li + k * 64]);
#pragma unroll
        for (int m = 1; m < 64; m <<= 1) mx = fmaxf(mx, __shfl_xor(mx, m));
        float pv[8];
        float sum = 0.f;
#pragma unroll
        for (int k = 0; k < 8; ++k) {
            float p = __expf(sl[r][li + k * 64] - mx);
            pv[k] = p;
            sum += p;
        }
#pragma unroll
        for (int m = 1; m < 64; m <<= 1) sum += __shfl_xor(sum, m);
        float inv = 1.f / sum;
#pragma unroll
        for (int k = 0; k < 8; ++k) {
            float a = pv[k] * inv;
            sl[r][li + k * 64] = a;
            attn_out[(size_t)(b0 + r) * 512 + li + k * 64] = a;
        }
    }
    __syncthreads();
    const int d = tid;
    float acc[8] = {};
    for (int t = 0; t < 512; t += 2) {
        float m0v = mem[(size_t)t * 512 + d];
        float m1v = mem[(size_t)(t + 1) * 512 + d];
#pragma unroll
        for (int r = 0; r < 8; ++r) {
            acc[r] += sl[r][t] * m0v;
            acc[r] += sl[r][t + 1] * m1v;
        }
    }
#pragma unroll
    for (int r = 0; r < 8; ++r) {
        int b = b0 + r;
        ct_out[(size_t)b * 512 + d] = acc[r];
        hc_bf[(size_t)b * 768 + 256 + d] = (unsigned short)f2bf1(acc[r]);
    }
}

// ---------------------------------------------------------------------------
// Finish: fused {rowsum over ps (coalesced, transposed layout) + p_gen dot}
// -> scale bf16 exp-stash into f32 row + extra_zeros, coverage copy,
// scatter-add. 512 blocks x 1024 thr.
// ---------------------------------------------------------------------------
__global__ __launch_bounds__(1024) void finish_k(float* __restrict__ outF,
                                                 const float* __restrict__ ps,
                                                 const float* __restrict__ ct,
                                                 const float* __restrict__ scat,
                                                 const float* __restrict__ xw,
                                                 const float* __restrict__ Wpg,
                                                 const float* __restrict__ bpg,
                                                 float* __restrict__ outPG,
                                                 const float* __restrict__ ez,
                                                 const float* __restrict__ attn,
                                                 const int* __restrict__ ebev,
                                                 const float* __restrict__ cov,
                                                 float* __restrict__ outCov) {
    const int b = blockIdx.x;
    const int tid = threadIdx.x;
    __shared__ float sred[16], pgred[16], shsc[2];

    // --- fused rowsum + p_gen (ps row is contiguous: coalesced read) ---
    float sp = 0.f;
    if (tid < 2 * NCB_)
        sp = ps[(size_t)b * (2 * NCB_) + tid];
    float pgp = 0.f;
    for (int idx = tid; idx < 1280; idx += 1024) {
        float wv = Wpg[idx];
        float xv;
        if (idx < 512) xv = ct[(size_t)b * 512 + idx];
        else if (idx < 1024) xv = scat[(size_t)b * 512 + idx - 512];
        else xv = xw[(size_t)b * 256 + idx - 1024];
        pgp += wv * xv;
    }
#pragma unroll
    for (int m = 1; m < 64; m <<= 1) {
        sp += __shfl_xor(sp, m);
        pgp += __shfl_xor(pgp, m);
    }
    if ((tid & 63) == 0) { sred[tid >> 6] = sp; pgred[tid >> 6] = pgp; }
    __syncthreads();
    if (tid == 0) {
        float s = 0.f, pg = 0.f;
#pragma unroll
        for (int i = 0; i < 16; ++i) { s += sred[i]; pg += pgred[i]; }
        float pgv = fast_sig(pg + bpg[0]);
        outPG[b] = pgv;
        shsc[0] = pgv / s;
        shsc[1] = 1.f - pgv;
    }
    __syncthreads();
    const float s = shsc[0];
    const float ad = shsc[1];

    // --- scale stash -> f32 row (in-place safe: read all, barrier, write) ---
    float* row = outF + (size_t)b * VE_;
    const unsigned short* el = (const unsigned short*)(row + ELOFF);
    uint2 buf[13];
    float4 ezbuf;
#pragma unroll
    for (int k = 0; k < 13; ++k) {
        int c4 = tid + (k << 10);
        if (c4 < 12500)
            buf[k] = *reinterpret_cast<const uint2*>(el + c4 * 4);
        else if (c4 < 12516)
            ezbuf = *reinterpret_cast<const float4*>(&ez[(size_t)b * NOOV_ + (c4 - 12500) * 4]);
    }
    __syncthreads();
#pragma unroll
    for (int k = 0; k < 13; ++k) {
        int c4 = tid + (k << 10);
        if (c4 < 12500) {
            uint2 e = buf[k];
            float4 v;
            v.x = __uint_as_float((e.x & 0xffffu) << 16) * s;
            v.y = __uint_as_float(e.x & 0xffff0000u) * s;
            v.z = __uint_as_float((e.y & 0xffffu) << 16) * s;
            v.w = __uint_as_float(e.y & 0xffff0000u) * s;
            *reinterpret_cast<float4*>(row + c4 * 4) = v;
        } else if (c4 < 12516) {
            *reinterpret_cast<float4*>(row + c4 * 4) = ezbuf;
        }
    }
    if (tid < 128)
        reinterpret_cast<float4*>(outCov + (size_t)b * 512)[tid] =
            reinterpret_cast<const float4*>(cov + (size_t)b * 512)[tid];
    __syncthreads();
    if (tid < 512) {
        int col = ebev[(size_t)b * 512 + tid];
        float val = ad * attn[(size_t)b * 512 + tid];
        atomicAdd(&row[col], val);
    }
}

// ---------------------------------------------------------------------------
extern "C" void kernel_launch(void* const* d_in, const int* in_sizes, int n_in,
                              void* d_out, int out_size, void* d_ws, size_t ws_size,
                              hipStream_t stream) {
    const int*   y    = (const int*)d_in[0];
    const float* h0   = (const float*)d_in[1];
    const float* c0   = (const float*)d_in[2];
    const float* ct1  = (const float*)d_in[3];
    const float* ez   = (const float*)d_in[4];
    const int*   ebev = (const int*)d_in[5];
    const float* cov  = (const float*)d_in[6];
    const float* emb  = (const float*)d_in[7];
    const float* Wx   = (const float*)d_in[8];
    const float* bx   = (const float*)d_in[9];
    const float* Wih  = (const float*)d_in[10];
    const float* Whh  = (const float*)d_in[11];
    const float* bih  = (const float*)d_in[12];
    const float* bhh  = (const float*)d_in[13];
    const float* memp = (const float*)d_in[14];
    const float* Wdp  = (const float*)d_in[15];
    const float* bdp  = (const float*)d_in[16];
    const float* vw   = (const float*)d_in[17];
    const float* Wpg  = (const float*)d_in[18];
    const float* bpg  = (const float*)d_in[19];
    const float* Wo1  = (const float*)d_in[20];
    const float* bo1  = (const float*)d_in[21];
    const float* Wo2  = (const float*)d_in[22];
    const float* bo2  = (const float*)d_in[23];

    float* out = (float*)d_out;
    const size_t OUT_FINAL = 0;
    const size_t OUT_H    = (size_t)B_ * VE_;
    const size_t OUT_C    = OUT_H + (size_t)B_ * H_;
    const size_t OUT_CT   = OUT_C + (size_t)B_ * H_;
    const size_t OUT_ATTN = OUT_CT + (size_t)B_ * 2 * H_;
    const size_t OUT_PG   = OUT_ATTN + (size_t)B_ * TK_;
    const size_t OUT_COV  = OUT_PG + B_;

    // ---- workspace layout ----
    char* wb = (char*)d_ws;
    float* xw     = (float*)wb;                       // 131072
    float* scat   = xw + 131072;                      // 262144
    float* Ed     = scat + 262144;                    // 262144
    float* scores = Ed + 262144;                      // 262144
    float* ps     = scores + 262144;                  // 400384
    float* Em     = ps + 400384;                      // 262144
    float* bsum   = Em + 262144;                      // 1024
    unsigned short* Wx_bf   = (unsigned short*)(bsum + 1024);
    unsigned short* Wcat_bf = Wx_bf + 196608;
    unsigned short* Wdp_bf  = Wcat_bf + 524288;
    unsigned short* Wo1_bf  = Wdp_bf + 262144;
    unsigned short* xcat_bf = Wo1_bf + 196608;
    unsigned short* xh_bf   = xcat_bf + 393216;
    unsigned short* scat_bf = xh_bf + 262144;
    unsigned short* hc_bf   = scat_bf + 262144;
    unsigned short* out1_bf = hc_bf + 393216;
    unsigned short* Wo2_bf  = out1_bf + 131072;       // 50176*256 ushorts

    // 0) small conversions / gathers (Wcat gate-interleaved, Em=exp(2*mem))
    prep_small<<<(PR_END + 255) / 256, 256, 0, stream>>>(
        Wx, Wdp, Wo1, Wih, Whh, bih, bhh, y, ct1, emb, h0, memp,
        Wx_bf, Wdp_bf, Wo1_bf, Wcat_bf, xcat_bf, xh_bf, Em, bsum);

    // 1) x = cat(c_t_1, emb[y]) @ Wx^T + bx  -> f32 xw + bf16 into xh_bf[:,0:256]
    gemm64<<<dim3(4, 8), 256, 0, stream>>>(xcat_bf, Wx_bf, bx, xw, xh_bf,
                                           256, 768, 512, 0, 0);

    // 2) LSTM gates GEMM + fused pointwise
    gemm_lstm<<<dim3(16, 8), 256, 0, stream>>>(xh_bf, Wcat_bf, bsum, c0,
                                               out + OUT_H, out + OUT_C,
                                               scat, scat_bf, hc_bf);

    // 3) attention: Ed = exp(2*(s_t_hat @ Wdp^T + bdp)) via mode=2 epilogue
    gemm64<<<dim3(8, 8), 256, 0, stream>>>(scat_bf, Wdp_bf, bdp, Ed, nullptr,
                                           512, 512, 0, 0, 2);
    attn_conv<<<7296, 256, 0, stream>>>(Em, Ed, vw, scores, Wo2, Wo2_bf);
    softmax_ct<<<64, 512, 0, stream>>>(scores, memp, out + OUT_ATTN,
                                       out + OUT_CT, hc_bf);

    // 4) vocab distribution: out1 -> exp-stash + partial sums
    gemm64<<<dim3(4, 8), 256, 0, stream>>>(hc_bf, Wo1_bf, bo1, nullptr, out1_bf,
                                           256, 768, 256, 0, 1);
    gemm_sum<<<1564, 1024, 0, stream>>>(out1_bf, Wo2_bf, bo2, out + OUT_FINAL, ps);

    // 5) finish: rowsum + p_gen + scale + extra_zeros + coverage + scatter
    finish_k<<<512, 1024, 0, stream>>>(out + OUT_FINAL, ps, out + OUT_CT, scat,
                                       xw, Wpg, bpg, out + OUT_PG, ez,
                                       out + OUT_ATTN, ebev, cov, out + OUT_COV);
}